// Round 5
// baseline (599.332 us; speedup 1.0000x reference)
//
#include <hip/hip_runtime.h>
#include <hip/hip_bf16.h>
#include <math.h>

#define N_NODES 100000
#define EMB 128
#define N_EDGES 1600000
#define N_LAYERS 3
#define SCAN_BLK 256
#define N_SCAN_BLOCKS ((N_NODES + SCAN_BLK - 1) / SCAN_BLK)  // 391
#define NBKT 8
#define BKT_CAP 204800  // expected 200000 +- ~420 (3 sigma); generous slack

typedef __bf16 bf16x8 __attribute__((ext_vector_type(8)));
typedef float f32x4 __attribute__((ext_vector_type(4)));

// ---------------- CSR build ----------------

__global__ __launch_bounds__(256) void hist_kernel(const int* __restrict__ dst,
                                                   int* __restrict__ counts) {
  int i = blockIdx.x * 256 + threadIdx.x;
  if (i < N_EDGES) atomicAdd(&counts[dst[i]], 1);
}

__global__ __launch_bounds__(256) void scan1_kernel(const int* __restrict__ counts,
                                                    int* __restrict__ partials) {
  __shared__ int sdata[256];
  int t = threadIdx.x;
  int idx = blockIdx.x * 256 + t;
  sdata[t] = (idx < N_NODES) ? counts[idx] : 0;
  __syncthreads();
  for (int off = 128; off > 0; off >>= 1) {
    if (t < off) sdata[t] += sdata[t + off];
    __syncthreads();
  }
  if (t == 0) partials[blockIdx.x] = sdata[0];
}

__global__ __launch_bounds__(512) void scan2_kernel(int* __restrict__ partials) {
  __shared__ int s[512];
  int t = threadIdx.x;
  int v = (t < N_SCAN_BLOCKS) ? partials[t] : 0;
  s[t] = v;
  __syncthreads();
  for (int off = 1; off < 512; off <<= 1) {
    int tmp = (t >= off) ? s[t - off] : 0;
    __syncthreads();
    s[t] += tmp;
    __syncthreads();
  }
  if (t < N_SCAN_BLOCKS) partials[t] = s[t] - v;  // exclusive prefix of block sums
}

__global__ __launch_bounds__(256) void scan3_kernel(const int* __restrict__ counts,
                                                    const int* __restrict__ partials,
                                                    int* __restrict__ row_ptr,
                                                    int* __restrict__ cursor) {
  __shared__ int s[256];
  int t = threadIdx.x;
  int b = blockIdx.x;
  int idx = b * 256 + t;
  int v = (idx < N_NODES) ? counts[idx] : 0;
  s[t] = v;
  __syncthreads();
  for (int off = 1; off < 256; off <<= 1) {
    int tmp = (t >= off) ? s[t - off] : 0;
    __syncthreads();
    s[t] += tmp;
    __syncthreads();
  }
  if (idx < N_NODES) {
    int val = s[t] - v + partials[b];
    row_ptr[idx] = val;
    cursor[idx] = val;
  }
  if (b == 0 && t == 0) row_ptr[N_NODES] = N_EDGES;
}

// Pass A: partition edges into 8 dst-range buckets of (src,dst) pairs.
// Block-local LDS counting -> one global atomic per (block,bucket) -> writes
// are contiguous ~2KB runs per (block,bucket): write amp ~1.
__global__ __launch_bounds__(256) void bucket_kernel(const int* __restrict__ src,
                                                     const int* __restrict__ dst,
                                                     int* __restrict__ bcur,
                                                     uint2* __restrict__ pairs) {
  __shared__ int scnt[NBKT];
  __shared__ int sbase[NBKT];
  int t = threadIdx.x;
  if (t < NBKT) scnt[t] = 0;
  __syncthreads();
  int i = blockIdx.x * 256 + t;  // grid exact: 6250 blocks
  int d = dst[i];
  int s = src[i];
  int bkt = d / (N_NODES / NBKT);
  int lofs = atomicAdd(&scnt[bkt], 1);
  __syncthreads();
  if (t < NBKT) sbase[t] = atomicAdd(&bcur[t], scnt[t]);
  __syncthreads();
  pairs[(size_t)bkt * BKT_CAP + sbase[bkt] + lofs] = make_uint2((unsigned)s, (unsigned)d);
}

// Pass B: each block reads ONLY its bucket's pairs (no L2 thrash); the 800KB
// col region per bucket stays L2-resident so the 16 writes/line merge.
// bucket = blockIdx&7 (round-robin -> same-XCD heuristic), chunk = blockIdx>>3.
__global__ __launch_bounds__(256) void fill2_kernel(const uint2* __restrict__ pairs,
                                                    const int* __restrict__ bcnt,
                                                    int* __restrict__ cursor,
                                                    int* __restrict__ col) {
  int b = blockIdx.x & 7;
  int chunk = blockIdx.x >> 3;  // 0..63
  int n = bcnt[b];
  int per = (n + 63) / 64;
  int lo = chunk * per;
  int hi = lo + per < n ? lo + per : n;
  const uint2* p = pairs + (size_t)b * BKT_CAP;
  for (int i = lo + threadIdx.x; i < hi; i += 256) {
    uint2 e = p[i];
    int pos = atomicAdd(&cursor[e.y], 1);
    col[pos] = (int)e.x;
  }
}

// ---------------- precompute ----------------

// x = node_emb (fp32 copy), xb = bf16(node_emb); 8 elems/thread
__global__ __launch_bounds__(256) void convert_kernel(const float* __restrict__ in,
                                                      float* __restrict__ x,
                                                      __hip_bfloat16* __restrict__ xb) {
  size_t i = (size_t)blockIdx.x * 256 + threadIdx.x;  // 1.6M threads exactly
  const float4* p = (const float4*)in + i * 2;
  float4 a = p[0], b = p[1];
  float4* xo = (float4*)x + i * 2;
  xo[0] = a;
  xo[1] = b;
  union { __hip_bfloat16 h[8]; uint4 u; } r;
  r.h[0] = __float2bfloat16(a.x); r.h[1] = __float2bfloat16(a.y);
  r.h[2] = __float2bfloat16(a.z); r.h[3] = __float2bfloat16(a.w);
  r.h[4] = __float2bfloat16(b.x); r.h[5] = __float2bfloat16(b.y);
  r.h[6] = __float2bfloat16(b.z); r.h[7] = __float2bfloat16(b.w);
  ((uint4*)xb)[i] = r.u;
}

// WT[l][col][k] = bf16(W[l][k][col]) — MFMA B-frag wants contiguous k per col
__global__ __launch_bounds__(256) void wt_kernel(const float* __restrict__ W,
                                                 __hip_bfloat16* __restrict__ WT) {
  int l = blockIdx.x;
  const float* Wl = W + (size_t)l * EMB * EMB;
  __hip_bfloat16* WTl = WT + (size_t)l * EMB * EMB;
  for (int i = threadIdx.x; i < EMB * EMB; i += 256) {
    int k = i >> 7, c = i & 127;
    WTl[c * EMB + k] = __float2bfloat16(Wl[i]);
  }
}

// ---------------- per-layer compute ----------------

__device__ __forceinline__ float bf_lo(unsigned int w) { return __uint_as_float(w << 16); }
__device__ __forceinline__ float bf_hi(unsigned int w) { return __uint_as_float(w & 0xFFFF0000u); }

// one wave per node: m[v] = bf16( deg_inv[v] * sum_{u in N(v)} xb[u] )
// 2 rows per vector load (uint2/lane, 32 lanes/row, half-wave per edge);
// 4-pair unroll = 8 edges/iter, 4x 512B loads in flight.
__global__ __launch_bounds__(256) void aggregate_kernel(const __hip_bfloat16* __restrict__ xb,
                                                        const int* __restrict__ row_ptr,
                                                        const int* __restrict__ col,
                                                        const float* __restrict__ deg_inv,
                                                        __hip_bfloat16* __restrict__ mb) {
  int gw = (blockIdx.x * 256 + threadIdx.x) >> 6;
  int lane = threadIdx.x & 63;
  int v = __builtin_amdgcn_readfirstlane(gw);  // wave-uniform node id -> SGPR
  if (v >= N_NODES) return;
  int beg = row_ptr[v];
  int end = row_ptr[v + 1];
  const int half = lane >> 5;   // which edge of a pair this half-wave handles
  const int l31 = lane & 31;
  const char* base = (const char*)xb + l31 * 8;  // 4 bf16 per lane
  float a0 = 0.f, a1 = 0.f, a2 = 0.f, a3 = 0.f;
  int e = beg;
  for (; e + 8 <= end; e += 8) {
    int u0 = col[e + half];
    int u1 = col[e + 2 + half];
    int u2 = col[e + 4 + half];
    int u3 = col[e + 6 + half];
    uint2 w0 = *(const uint2*)(base + (size_t)u0 * (EMB * 2));
    uint2 w1 = *(const uint2*)(base + (size_t)u1 * (EMB * 2));
    uint2 w2 = *(const uint2*)(base + (size_t)u2 * (EMB * 2));
    uint2 w3 = *(const uint2*)(base + (size_t)u3 * (EMB * 2));
    a0 += bf_lo(w0.x) + bf_lo(w1.x) + bf_lo(w2.x) + bf_lo(w3.x);
    a1 += bf_hi(w0.x) + bf_hi(w1.x) + bf_hi(w2.x) + bf_hi(w3.x);
    a2 += bf_lo(w0.y) + bf_lo(w1.y) + bf_lo(w2.y) + bf_lo(w3.y);
    a3 += bf_hi(w0.y) + bf_hi(w1.y) + bf_hi(w2.y) + bf_hi(w3.y);
  }
  for (; e + 2 <= end; e += 2) {
    int u = col[e + half];
    uint2 w = *(const uint2*)(base + (size_t)u * (EMB * 2));
    a0 += bf_lo(w.x); a1 += bf_hi(w.x); a2 += bf_lo(w.y); a3 += bf_hi(w.y);
  }
  if (e < end && half == 0) {  // odd tail: lower half only
    int u = col[e];
    uint2 w = *(const uint2*)(base + (size_t)u * (EMB * 2));
    a0 += bf_lo(w.x); a1 += bf_hi(w.x); a2 += bf_lo(w.y); a3 += bf_hi(w.y);
  }
  a0 += __shfl_xor(a0, 32, 64);
  a1 += __shfl_xor(a1, 32, 64);
  a2 += __shfl_xor(a2, 32, 64);
  a3 += __shfl_xor(a3, 32, 64);
  if (half == 0) {
    float di = deg_inv[v];
    union { __hip_bfloat16 h[4]; uint2 u; } r;
    r.h[0] = __float2bfloat16(a0 * di);
    r.h[1] = __float2bfloat16(a1 * di);
    r.h[2] = __float2bfloat16(a2 * di);
    r.h[3] = __float2bfloat16(a3 * di);
    *(uint2*)((char*)mb + (size_t)v * (EMB * 2) + l31 * 8) = r.u;
  }
}

__device__ __forceinline__ float gelu_exact(float v) {
  return 0.5f * v * (1.f + erff(v * 0.70710678118654752f));
}

// x[row] += gelu(m[row] @ W + bias)   via bf16 MFMA, fp32 accum.
// 3125 blocks x 32 rows (exact). 4 waves: wave w -> rows (w>>1)*16, cols (w&1)*64.
// B-frags (W^T) held in registers: 4 coltiles x 4 ksteps x bf16x8. No LDS.
__global__ __launch_bounds__(256) void gemm_kernel(const __hip_bfloat16* __restrict__ mb,
                                                   const __hip_bfloat16* __restrict__ WTl,
                                                   const float* __restrict__ bias,
                                                   float* __restrict__ x,
                                                   __hip_bfloat16* __restrict__ xb,
                                                   int write_xb) {
  const int lane = threadIdx.x & 63;
  const int wave = threadIdx.x >> 6;
  const int rh = wave >> 1;        // row half
  const int ch = wave & 1;         // col half
  const int row0 = blockIdx.x * 32 + rh * 16;
  const int l15 = lane & 15;
  const int lhi = lane >> 4;       // 0..3

  // load B fragments: lane holds WT[col][kb..kb+8), col = ch*64+ct*16+l15
  bf16x8 bf[4][4];
#pragma unroll
  for (int ct = 0; ct < 4; ++ct) {
    const __hip_bfloat16* wp = WTl + (size_t)(ch * 64 + ct * 16 + l15) * EMB + lhi * 8;
#pragma unroll
    for (int ks = 0; ks < 4; ++ks)
      bf[ct][ks] = *(const bf16x8*)(wp + ks * 32);
  }

  // A fragments: lane holds mb[row0+l15][kb..kb+8)
  const bf16x8* ap = (const bf16x8*)(mb + (size_t)(row0 + l15) * EMB + lhi * 8);

  f32x4 acc[4];
#pragma unroll
  for (int ct = 0; ct < 4; ++ct) acc[ct] = (f32x4)(0.f);

#pragma unroll
  for (int ks = 0; ks < 4; ++ks) {
    bf16x8 af = ap[ks * 4];  // +32 bf16 per kstep
#pragma unroll
    for (int ct = 0; ct < 4; ++ct)
      acc[ct] = __builtin_amdgcn_mfma_f32_16x16x32_bf16(af, bf[ct][ks], acc[ct], 0, 0, 0);
  }

  // epilogue: C[row][col], row = row0 + lhi*4 + j, col = ch*64 + ct*16 + l15
#pragma unroll
  for (int ct = 0; ct < 4; ++ct) {
    const int colg = ch * 64 + ct * 16 + l15;
    const float bb = bias[colg];
#pragma unroll
    for (int j = 0; j < 4; ++j) {
      const int row = row0 + lhi * 4 + j;
      const size_t off = (size_t)row * EMB + colg;
      float xv = x[off] + gelu_exact(acc[ct][j] + bb);
      x[off] = xv;
      if (write_xb) xb[off] = __float2bfloat16(xv);
    }
  }
}

// in-place LayerNorm over feature dim; one wave per row
__global__ __launch_bounds__(256) void ln_kernel(float* __restrict__ x,
                                                 const float* __restrict__ gamma,
                                                 const float* __restrict__ beta) {
  int gw = (blockIdx.x * 256 + threadIdx.x) >> 6;
  int lane = threadIdx.x & 63;
  if (gw >= N_NODES) return;
  float* xp = x + (size_t)gw * EMB + lane * 2;
  float2 v = *(const float2*)xp;
  float s = v.x + v.y;
  float sq = fmaf(v.x, v.x, v.y * v.y);
  for (int off = 1; off < 64; off <<= 1) {
    s += __shfl_xor(s, off, 64);
    sq += __shfl_xor(sq, off, 64);
  }
  float mu = s * (1.f / EMB);
  float var = sq * (1.f / EMB) - mu * mu;
  float rstd = rsqrtf(var + 1e-5f);
  float2 g = *(const float2*)(gamma + lane * 2);
  float2 be = *(const float2*)(beta + lane * 2);
  float2 o;
  o.x = (v.x - mu) * rstd * g.x + be.x;
  o.y = (v.y - mu) * rstd * g.y + be.y;
  *(float2*)xp = o;
}

// ---------------- launch ----------------

extern "C" void kernel_launch(void* const* d_in, const int* in_sizes, int n_in,
                              void* d_out, int out_size, void* d_ws, size_t ws_size,
                              hipStream_t stream) {
  const int* edge_index = (const int*)d_in[0];
  const float* deg_inv = (const float*)d_in[1];
  const float* node_emb = (const float*)d_in[2];
  const float* W = (const float*)d_in[3];
  const float* b = (const float*)d_in[4];
  const float* gamma = (const float*)d_in[5];
  const float* beta = (const float*)d_in[6];
  const int* src = edge_index;
  const int* dst = edge_index + N_EDGES;
  float* x = (float*)d_out;  // fp32 residual stream lives in d_out

  // workspace layout (offsets padded to 256B)
  char* ws = (char*)d_ws;
  auto take = [&](size_t bytes) {
    char* p = ws;
    ws += (bytes + 255) & ~(size_t)255;
    return p;
  };
  __hip_bfloat16* xb = (__hip_bfloat16*)take((size_t)N_NODES * EMB * 2);  // bf16 shadow of x
  __hip_bfloat16* mb = (__hip_bfloat16*)take((size_t)N_NODES * EMB * 2);  // bf16 aggregate
  __hip_bfloat16* WT = (__hip_bfloat16*)take((size_t)N_LAYERS * EMB * EMB * 2);
  int* counts = (int*)take(N_NODES * sizeof(int));
  int* row_ptr = (int*)take((N_NODES + 1) * sizeof(int));
  int* cursor = (int*)take(N_NODES * sizeof(int));
  int* col = (int*)take(N_EDGES * sizeof(int));
  int* partials = (int*)take(512 * sizeof(int));
  int* bcur = (int*)take(NBKT * sizeof(int));
  uint2* pairs = (uint2*)mb;  // alias: CSR build finishes before layer-0 aggregate

  hipMemsetAsync(counts, 0, N_NODES * sizeof(int), stream);
  hipMemsetAsync(bcur, 0, NBKT * sizeof(int), stream);

  convert_kernel<<<N_NODES * EMB / 8 / 256, 256, 0, stream>>>(node_emb, x, xb);
  wt_kernel<<<N_LAYERS, 256, 0, stream>>>(W, WT);

  hist_kernel<<<(N_EDGES + 255) / 256, 256, 0, stream>>>(dst, counts);
  scan1_kernel<<<N_SCAN_BLOCKS, 256, 0, stream>>>(counts, partials);
  scan2_kernel<<<1, 512, 0, stream>>>(partials);
  scan3_kernel<<<N_SCAN_BLOCKS, 256, 0, stream>>>(counts, partials, row_ptr, cursor);
  bucket_kernel<<<N_EDGES / 256, 256, 0, stream>>>(src, dst, bcur, pairs);
  fill2_kernel<<<512, 256, 0, stream>>>(pairs, bcur, cursor, col);

  for (int l = 0; l < N_LAYERS; ++l) {
    aggregate_kernel<<<(N_NODES + 3) / 4, 256, 0, stream>>>(xb, row_ptr, col, deg_inv, mb);
    gemm_kernel<<<N_NODES / 32, 256, 0, stream>>>(mb, WT + (size_t)l * EMB * EMB,
                                                  b + (size_t)l * EMB, x, xb,
                                                  l < N_LAYERS - 1 ? 1 : 0);
  }
  ln_kernel<<<(N_NODES + 3) / 4, 256, 0, stream>>>(x, gamma, beta);
}

// Round 6
// 545.548 us; speedup vs baseline: 1.0986x; 1.0986x over previous
//
#include <hip/hip_runtime.h>
#include <hip/hip_bf16.h>
#include <math.h>

#define N_NODES 100000
#define EMB 128
#define N_EDGES 1600000
#define N_LAYERS 3
#define SCAN_BLK 256
#define N_SCAN_BLOCKS ((N_NODES + SCAN_BLK - 1) / SCAN_BLK)  // 391
#define NBKT 8
#define BKT_CAP 204800   // expected 200000 +- ~420 (3 sigma); generous slack
#define BCUR_STRIDE 64   // ints; pad bucket counters 256B apart -> parallel L2 atomics
#define EPT 8            // edges per thread in bucket pass
#define BUCKET_BLOCKS ((N_EDGES + 256 * EPT - 1) / (256 * EPT))  // 782

typedef __bf16 bf16x8 __attribute__((ext_vector_type(8)));
typedef float f32x4 __attribute__((ext_vector_type(4)));

// ---------------- CSR build ----------------

__global__ __launch_bounds__(256) void hist_kernel(const int* __restrict__ dst,
                                                   int* __restrict__ counts) {
  int i = blockIdx.x * 256 + threadIdx.x;
  if (i < N_EDGES) atomicAdd(&counts[dst[i]], 1);
}

__global__ __launch_bounds__(256) void scan1_kernel(const int* __restrict__ counts,
                                                    int* __restrict__ partials) {
  __shared__ int sdata[256];
  int t = threadIdx.x;
  int idx = blockIdx.x * 256 + t;
  sdata[t] = (idx < N_NODES) ? counts[idx] : 0;
  __syncthreads();
  for (int off = 128; off > 0; off >>= 1) {
    if (t < off) sdata[t] += sdata[t + off];
    __syncthreads();
  }
  if (t == 0) partials[blockIdx.x] = sdata[0];
}

__global__ __launch_bounds__(512) void scan2_kernel(int* __restrict__ partials) {
  __shared__ int s[512];
  int t = threadIdx.x;
  int v = (t < N_SCAN_BLOCKS) ? partials[t] : 0;
  s[t] = v;
  __syncthreads();
  for (int off = 1; off < 512; off <<= 1) {
    int tmp = (t >= off) ? s[t - off] : 0;
    __syncthreads();
    s[t] += tmp;
    __syncthreads();
  }
  if (t < N_SCAN_BLOCKS) partials[t] = s[t] - v;  // exclusive prefix of block sums
}

__global__ __launch_bounds__(256) void scan3_kernel(const int* __restrict__ counts,
                                                    const int* __restrict__ partials,
                                                    int* __restrict__ row_ptr,
                                                    int* __restrict__ cursor) {
  __shared__ int s[256];
  int t = threadIdx.x;
  int b = blockIdx.x;
  int idx = b * 256 + t;
  int v = (idx < N_NODES) ? counts[idx] : 0;
  s[t] = v;
  __syncthreads();
  for (int off = 1; off < 256; off <<= 1) {
    int tmp = (t >= off) ? s[t - off] : 0;
    __syncthreads();
    s[t] += tmp;
    __syncthreads();
  }
  if (idx < N_NODES) {
    int val = s[t] - v + partials[b];
    row_ptr[idx] = val;
    cursor[idx] = val;
  }
  if (b == 0 && t == 0) row_ptr[N_NODES] = N_EDGES;
}

// Pass A v2: partition edges into 8 dst-range buckets of (src,dst) pairs.
// 8 edges/thread (held in registers), per-block LDS counts, then ONE padded
// global atomic per (block,bucket) -> 6.3K atomics on 8 separate lines.
__global__ __launch_bounds__(256) void bucket_kernel(const int* __restrict__ src,
                                                     const int* __restrict__ dst,
                                                     int* __restrict__ bcur,
                                                     uint2* __restrict__ pairs) {
  __shared__ int scnt[NBKT];
  __shared__ int sbase[NBKT];
  const int t = threadIdx.x;
  if (t < NBKT) scnt[t] = 0;
  __syncthreads();
  int sreg[EPT], dreg[EPT], bk[EPT], lofs[EPT];
  const int base_e = blockIdx.x * 256 * EPT;
#pragma unroll
  for (int it = 0; it < EPT; ++it) {
    int i = base_e + it * 256 + t;
    bk[it] = -1;
    if (i < N_EDGES) {
      dreg[it] = dst[i];
      sreg[it] = src[i];
      bk[it] = dreg[it] / (N_NODES / NBKT);
      lofs[it] = atomicAdd(&scnt[bk[it]], 1);
    }
  }
  __syncthreads();
  if (t < NBKT) sbase[t] = atomicAdd(&bcur[t * BCUR_STRIDE], scnt[t]);
  __syncthreads();
#pragma unroll
  for (int it = 0; it < EPT; ++it) {
    if (bk[it] >= 0) {
      pairs[(size_t)bk[it] * BKT_CAP + sbase[bk[it]] + lofs[it]] =
          make_uint2((unsigned)sreg[it], (unsigned)dreg[it]);
    }
  }
}

// Pass B: each block reads ONLY its bucket's pairs (no L2 thrash); the 800KB
// col region per bucket stays L2-resident so the 16 writes/line merge.
// bucket = blockIdx&7 (round-robin -> same-XCD heuristic), chunk = blockIdx>>3.
__global__ __launch_bounds__(256) void fill2_kernel(const uint2* __restrict__ pairs,
                                                    const int* __restrict__ bcnt,
                                                    int* __restrict__ cursor,
                                                    int* __restrict__ col) {
  int b = blockIdx.x & 7;
  int chunk = blockIdx.x >> 3;  // 0..255
  int n = bcnt[b * BCUR_STRIDE];
  int per = (n + 255) / 256;
  int lo = chunk * per;
  int hi = lo + per < n ? lo + per : n;
  const uint2* p = pairs + (size_t)b * BKT_CAP;
  for (int i = lo + threadIdx.x; i < hi; i += 256) {
    uint2 e = p[i];
    int pos = atomicAdd(&cursor[e.y], 1);
    col[pos] = (int)e.x;
  }
}

// ---------------- precompute ----------------

// x = node_emb (fp32 copy), xb = bf16(node_emb); 8 elems/thread
__global__ __launch_bounds__(256) void convert_kernel(const float* __restrict__ in,
                                                      float* __restrict__ x,
                                                      __hip_bfloat16* __restrict__ xb) {
  size_t i = (size_t)blockIdx.x * 256 + threadIdx.x;  // 1.6M threads exactly
  const float4* p = (const float4*)in + i * 2;
  float4 a = p[0], b = p[1];
  float4* xo = (float4*)x + i * 2;
  xo[0] = a;
  xo[1] = b;
  union { __hip_bfloat16 h[8]; uint4 u; } r;
  r.h[0] = __float2bfloat16(a.x); r.h[1] = __float2bfloat16(a.y);
  r.h[2] = __float2bfloat16(a.z); r.h[3] = __float2bfloat16(a.w);
  r.h[4] = __float2bfloat16(b.x); r.h[5] = __float2bfloat16(b.y);
  r.h[6] = __float2bfloat16(b.z); r.h[7] = __float2bfloat16(b.w);
  ((uint4*)xb)[i] = r.u;
}

// WT[l][col][k] = bf16(W[l][k][col]) — MFMA B-frag wants contiguous k per col
__global__ __launch_bounds__(256) void wt_kernel(const float* __restrict__ W,
                                                 __hip_bfloat16* __restrict__ WT) {
  int l = blockIdx.x;
  const float* Wl = W + (size_t)l * EMB * EMB;
  __hip_bfloat16* WTl = WT + (size_t)l * EMB * EMB;
  for (int i = threadIdx.x; i < EMB * EMB; i += 256) {
    int k = i >> 7, c = i & 127;
    WTl[c * EMB + k] = __float2bfloat16(Wl[i]);
  }
}

// ---------------- per-layer compute ----------------

__device__ __forceinline__ float bf_lo(unsigned int w) { return __uint_as_float(w << 16); }
__device__ __forceinline__ float bf_hi(unsigned int w) { return __uint_as_float(w & 0xFFFF0000u); }

// one wave per node: m[v] = bf16( deg_inv[v] * sum_{u in N(v)} xb[u] )
// 2 rows per vector load (uint2/lane, 32 lanes/row, half-wave per edge);
// 4-pair unroll = 8 edges/iter, 4x 512B loads in flight.
__global__ __launch_bounds__(256) void aggregate_kernel(const __hip_bfloat16* __restrict__ xb,
                                                        const int* __restrict__ row_ptr,
                                                        const int* __restrict__ col,
                                                        const float* __restrict__ deg_inv,
                                                        __hip_bfloat16* __restrict__ mb) {
  int gw = (blockIdx.x * 256 + threadIdx.x) >> 6;
  int lane = threadIdx.x & 63;
  int v = __builtin_amdgcn_readfirstlane(gw);  // wave-uniform node id -> SGPR
  if (v >= N_NODES) return;
  int beg = row_ptr[v];
  int end = row_ptr[v + 1];
  const int half = lane >> 5;   // which edge of a pair this half-wave handles
  const int l31 = lane & 31;
  const char* base = (const char*)xb + l31 * 8;  // 4 bf16 per lane
  float a0 = 0.f, a1 = 0.f, a2 = 0.f, a3 = 0.f;
  int e = beg;
  for (; e + 8 <= end; e += 8) {
    int u0 = col[e + half];
    int u1 = col[e + 2 + half];
    int u2 = col[e + 4 + half];
    int u3 = col[e + 6 + half];
    uint2 w0 = *(const uint2*)(base + (size_t)u0 * (EMB * 2));
    uint2 w1 = *(const uint2*)(base + (size_t)u1 * (EMB * 2));
    uint2 w2 = *(const uint2*)(base + (size_t)u2 * (EMB * 2));
    uint2 w3 = *(const uint2*)(base + (size_t)u3 * (EMB * 2));
    a0 += bf_lo(w0.x) + bf_lo(w1.x) + bf_lo(w2.x) + bf_lo(w3.x);
    a1 += bf_hi(w0.x) + bf_hi(w1.x) + bf_hi(w2.x) + bf_hi(w3.x);
    a2 += bf_lo(w0.y) + bf_lo(w1.y) + bf_lo(w2.y) + bf_lo(w3.y);
    a3 += bf_hi(w0.y) + bf_hi(w1.y) + bf_hi(w2.y) + bf_hi(w3.y);
  }
  for (; e + 2 <= end; e += 2) {
    int u = col[e + half];
    uint2 w = *(const uint2*)(base + (size_t)u * (EMB * 2));
    a0 += bf_lo(w.x); a1 += bf_hi(w.x); a2 += bf_lo(w.y); a3 += bf_hi(w.y);
  }
  if (e < end && half == 0) {  // odd tail: lower half only
    int u = col[e];
    uint2 w = *(const uint2*)(base + (size_t)u * (EMB * 2));
    a0 += bf_lo(w.x); a1 += bf_hi(w.x); a2 += bf_lo(w.y); a3 += bf_hi(w.y);
  }
  a0 += __shfl_xor(a0, 32, 64);
  a1 += __shfl_xor(a1, 32, 64);
  a2 += __shfl_xor(a2, 32, 64);
  a3 += __shfl_xor(a3, 32, 64);
  if (half == 0) {
    float di = deg_inv[v];
    union { __hip_bfloat16 h[4]; uint2 u; } r;
    r.h[0] = __float2bfloat16(a0 * di);
    r.h[1] = __float2bfloat16(a1 * di);
    r.h[2] = __float2bfloat16(a2 * di);
    r.h[3] = __float2bfloat16(a3 * di);
    *(uint2*)((char*)mb + (size_t)v * (EMB * 2) + l31 * 8) = r.u;
  }
}

__device__ __forceinline__ float gelu_exact(float v) {
  return 0.5f * v * (1.f + erff(v * 0.70710678118654752f));
}

// x[row] += gelu(m[row] @ W + bias)   via bf16 MFMA, fp32 accum.
// 3125 blocks x 32 rows (exact). 4 waves: wave w -> rows (w>>1)*16, cols (w&1)*64.
// B-frags (W^T) held in registers: 4 coltiles x 4 ksteps x bf16x8. No LDS.
__global__ __launch_bounds__(256) void gemm_kernel(const __hip_bfloat16* __restrict__ mb,
                                                   const __hip_bfloat16* __restrict__ WTl,
                                                   const float* __restrict__ bias,
                                                   float* __restrict__ x,
                                                   __hip_bfloat16* __restrict__ xb,
                                                   int write_xb) {
  const int lane = threadIdx.x & 63;
  const int wave = threadIdx.x >> 6;
  const int rh = wave >> 1;        // row half
  const int ch = wave & 1;         // col half
  const int row0 = blockIdx.x * 32 + rh * 16;
  const int l15 = lane & 15;
  const int lhi = lane >> 4;       // 0..3

  // load B fragments: lane holds WT[col][kb..kb+8), col = ch*64+ct*16+l15
  bf16x8 bf[4][4];
#pragma unroll
  for (int ct = 0; ct < 4; ++ct) {
    const __hip_bfloat16* wp = WTl + (size_t)(ch * 64 + ct * 16 + l15) * EMB + lhi * 8;
#pragma unroll
    for (int ks = 0; ks < 4; ++ks)
      bf[ct][ks] = *(const bf16x8*)(wp + ks * 32);
  }

  // A fragments: lane holds mb[row0+l15][kb..kb+8)
  const bf16x8* ap = (const bf16x8*)(mb + (size_t)(row0 + l15) * EMB + lhi * 8);

  f32x4 acc[4];
#pragma unroll
  for (int ct = 0; ct < 4; ++ct) acc[ct] = (f32x4)(0.f);

#pragma unroll
  for (int ks = 0; ks < 4; ++ks) {
    bf16x8 af = ap[ks * 4];  // +32 bf16 per kstep
#pragma unroll
    for (int ct = 0; ct < 4; ++ct)
      acc[ct] = __builtin_amdgcn_mfma_f32_16x16x32_bf16(af, bf[ct][ks], acc[ct], 0, 0, 0);
  }

  // epilogue: C[row][col], row = row0 + lhi*4 + j, col = ch*64 + ct*16 + l15
#pragma unroll
  for (int ct = 0; ct < 4; ++ct) {
    const int colg = ch * 64 + ct * 16 + l15;
    const float bb = bias[colg];
#pragma unroll
    for (int j = 0; j < 4; ++j) {
      const int row = row0 + lhi * 4 + j;
      const size_t off = (size_t)row * EMB + colg;
      float xv = x[off] + gelu_exact(acc[ct][j] + bb);
      x[off] = xv;
      if (write_xb) xb[off] = __float2bfloat16(xv);
    }
  }
}

// in-place LayerNorm over feature dim; one wave per row
__global__ __launch_bounds__(256) void ln_kernel(float* __restrict__ x,
                                                 const float* __restrict__ gamma,
                                                 const float* __restrict__ beta) {
  int gw = (blockIdx.x * 256 + threadIdx.x) >> 6;
  int lane = threadIdx.x & 63;
  if (gw >= N_NODES) return;
  float* xp = x + (size_t)gw * EMB + lane * 2;
  float2 v = *(const float2*)xp;
  float s = v.x + v.y;
  float sq = fmaf(v.x, v.x, v.y * v.y);
  for (int off = 1; off < 64; off <<= 1) {
    s += __shfl_xor(s, off, 64);
    sq += __shfl_xor(sq, off, 64);
  }
  float mu = s * (1.f / EMB);
  float var = sq * (1.f / EMB) - mu * mu;
  float rstd = rsqrtf(var + 1e-5f);
  float2 g = *(const float2*)(gamma + lane * 2);
  float2 be = *(const float2*)(beta + lane * 2);
  float2 o;
  o.x = (v.x - mu) * rstd * g.x + be.x;
  o.y = (v.y - mu) * rstd * g.y + be.y;
  *(float2*)xp = o;
}

// ---------------- launch ----------------

extern "C" void kernel_launch(void* const* d_in, const int* in_sizes, int n_in,
                              void* d_out, int out_size, void* d_ws, size_t ws_size,
                              hipStream_t stream) {
  const int* edge_index = (const int*)d_in[0];
  const float* deg_inv = (const float*)d_in[1];
  const float* node_emb = (const float*)d_in[2];
  const float* W = (const float*)d_in[3];
  const float* b = (const float*)d_in[4];
  const float* gamma = (const float*)d_in[5];
  const float* beta = (const float*)d_in[6];
  const int* src = edge_index;
  const int* dst = edge_index + N_EDGES;
  float* x = (float*)d_out;  // fp32 residual stream lives in d_out

  // workspace layout (offsets padded to 256B)
  char* ws = (char*)d_ws;
  auto take = [&](size_t bytes) {
    char* p = ws;
    ws += (bytes + 255) & ~(size_t)255;
    return p;
  };
  __hip_bfloat16* xb = (__hip_bfloat16*)take((size_t)N_NODES * EMB * 2);  // bf16 shadow of x
  __hip_bfloat16* mb = (__hip_bfloat16*)take((size_t)N_NODES * EMB * 2);  // bf16 aggregate
  __hip_bfloat16* WT = (__hip_bfloat16*)take((size_t)N_LAYERS * EMB * EMB * 2);
  int* counts = (int*)take(N_NODES * sizeof(int));
  int* row_ptr = (int*)take((N_NODES + 1) * sizeof(int));
  int* cursor = (int*)take(N_NODES * sizeof(int));
  int* col = (int*)take(N_EDGES * sizeof(int));
  int* partials = (int*)take(512 * sizeof(int));
  int* bcur = (int*)take(NBKT * BCUR_STRIDE * sizeof(int));
  uint2* pairs = (uint2*)mb;  // alias: CSR build finishes before layer-0 aggregate

  hipMemsetAsync(counts, 0, N_NODES * sizeof(int), stream);
  hipMemsetAsync(bcur, 0, NBKT * BCUR_STRIDE * sizeof(int), stream);

  convert_kernel<<<N_NODES * EMB / 8 / 256, 256, 0, stream>>>(node_emb, x, xb);
  wt_kernel<<<N_LAYERS, 256, 0, stream>>>(W, WT);

  hist_kernel<<<(N_EDGES + 255) / 256, 256, 0, stream>>>(dst, counts);
  scan1_kernel<<<N_SCAN_BLOCKS, 256, 0, stream>>>(counts, partials);
  scan2_kernel<<<1, 512, 0, stream>>>(partials);
  scan3_kernel<<<N_SCAN_BLOCKS, 256, 0, stream>>>(counts, partials, row_ptr, cursor);
  bucket_kernel<<<BUCKET_BLOCKS, 256, 0, stream>>>(src, dst, bcur, pairs);
  fill2_kernel<<<2048, 256, 0, stream>>>(pairs, bcur, cursor, col);

  for (int l = 0; l < N_LAYERS; ++l) {
    aggregate_kernel<<<(N_NODES + 3) / 4, 256, 0, stream>>>(xb, row_ptr, col, deg_inv, mb);
    gemm_kernel<<<N_NODES / 32, 256, 0, stream>>>(mb, WT + (size_t)l * EMB * EMB,
                                                  b + (size_t)l * EMB, x, xb,
                                                  l < N_LAYERS - 1 ? 1 : 0);
  }
  ln_kernel<<<(N_NODES + 3) / 4, 256, 0, stream>>>(x, gamma, beta);
}

// Round 7
// 406.691 us; speedup vs baseline: 1.4737x; 1.3414x over previous
//
#include <hip/hip_runtime.h>
#include <hip/hip_bf16.h>
#include <math.h>

#define N_NODES 100000
#define EMB 128
#define N_EDGES 1600000
#define N_LAYERS 3

#define NB 400        // buckets
#define NPB 250       // nodes per bucket (400*250 = 100000)
#define CAP 8192      // pairs capacity per bucket in global (mean 4000, sigma 63)
#define CAPB 6144     // LDS stage capacity (fallback path if exceeded)
#define BSTR 16       // bcur padding stride in ints (64B apart -> parallel L2 atomics)
#define EPT 8         // edges per thread in bucket pass
#define BUCKET_THREADS 512
#define BUCKET_BLOCKS ((N_EDGES + BUCKET_THREADS * EPT - 1) / (BUCKET_THREADS * EPT))  // 391

typedef __bf16 bf16x8 __attribute__((ext_vector_type(8)));
typedef float f32x4 __attribute__((ext_vector_type(4)));

// ---------------- CSR build (2 kernels, LDS-staged, no global scatter amp) ----

// Pass A: partition edges into 400 dst-range buckets of packed (vloc<<17|src).
// Per-block LDS counts -> one padded global atomic per (block,bucket).
__global__ __launch_bounds__(BUCKET_THREADS) void bucket_kernel(
    const int* __restrict__ src, const int* __restrict__ dst,
    int* __restrict__ bcur, unsigned* __restrict__ pairs) {
  __shared__ int scnt[NB];
  __shared__ int sbase[NB];
  const int t = threadIdx.x;
  if (t < NB) scnt[t] = 0;
  __syncthreads();
  unsigned pk[EPT];
  int bk[EPT], lofs[EPT];
  const int base_e = blockIdx.x * BUCKET_THREADS * EPT;
#pragma unroll
  for (int it = 0; it < EPT; ++it) {
    int i = base_e + it * BUCKET_THREADS + t;
    bk[it] = -1;
    if (i < N_EDGES) {
      int d = dst[i];
      int s = src[i];
      int b = d / NPB;                    // const-div -> magic mul
      int vloc = d - b * NPB;             // < 250 (8 bits)
      bk[it] = b;
      pk[it] = ((unsigned)vloc << 17) | (unsigned)s;  // src < 2^17
      lofs[it] = atomicAdd(&scnt[b], 1);
    }
  }
  __syncthreads();
  if (t < NB) sbase[t] = atomicAdd(&bcur[t * BSTR], scnt[t]);
  __syncthreads();
#pragma unroll
  for (int it = 0; it < EPT; ++it) {
    if (bk[it] >= 0) {
      int idx = sbase[bk[it]] + lofs[it];
      if (idx < CAP) pairs[(size_t)bk[it] * CAP + idx] = pk[it];
    }
  }
}

// inclusive scan of 512 ints with 256 threads, ping-pong; caller barriers before.
__device__ __forceinline__ int* scan512(int* pin, int* pout, int t) {
  for (int off = 1; off < 512; off <<= 1) {
    for (int i = t; i < 512; i += 256) {
      int v = pin[i];
      if (i >= off) v += pin[i - off];
      pout[i] = v;
    }
    __syncthreads();
    int* tmp = pin; pin = pout; pout = tmp;
  }
  return pin;  // inclusive prefix
}

// Pass B: one block per bucket. Derives bucket base (scan of bcur), counts its
// 250 node degrees, scans them -> writes row_ptr segment, scatters col inside
// LDS, flushes coalesced. Write amp = 1; all scatter atomics in LDS.
__global__ __launch_bounds__(256) void fillb_kernel(const unsigned* __restrict__ pairs,
                                                    const int* __restrict__ bcur,
                                                    int* __restrict__ row_ptr,
                                                    int* __restrict__ col) {
  __shared__ int sA[512], sB[512];
  __shared__ int cnt[NPB], cur[NPB];
  __shared__ unsigned pstage[CAPB];
  __shared__ int colstage[CAPB];
  const int t = threadIdx.x;
  const int b = blockIdx.x;

  // bucket bases: inclusive scan of all 400 bucket counts
  for (int i = t; i < 512; i += 256) sA[i] = (i < NB) ? bcur[i * BSTR] : 0;
  __syncthreads();
  int* r = scan512(sA, sB, t);
  int base_b = b ? r[b - 1] : 0;
  int n = r[b] - base_b;
  if (n > CAP) n = CAP;
  const unsigned* pg = pairs + (size_t)b * CAP;
  const bool fits = (n <= CAPB);

  if (fits) for (int i = t; i < n; i += 256) pstage[i] = pg[i];
  if (t < NPB) cnt[t] = 0;
  __syncthreads();
  for (int i = t; i < n; i += 256) atomicAdd(&cnt[(fits ? pstage[i] : pg[i]) >> 17], 1);
  __syncthreads();
  for (int i = t; i < 512; i += 256) sA[i] = (i < NPB) ? cnt[i] : 0;
  __syncthreads();
  r = scan512(sA, sB, t);
  if (t < NPB) {
    int ex = r[t] - cnt[t];  // exclusive
    row_ptr[b * NPB + t] = base_b + ex;
    cur[t] = ex;
  }
  if (b == NB - 1 && t == 0) row_ptr[N_NODES] = N_EDGES;
  __syncthreads();
  for (int i = t; i < n; i += 256) {
    unsigned p = fits ? pstage[i] : pg[i];
    int pos = atomicAdd(&cur[p >> 17], 1);
    int s = (int)(p & 0x1FFFFu);
    if (fits) colstage[pos] = s;
    else col[base_b + pos] = s;  // rare fallback: direct global scatter
  }
  __syncthreads();
  if (fits) for (int i = t; i < n; i += 256) col[base_b + i] = colstage[i];
}

// ---------------- precompute ----------------

// xb = bf16(node_emb); 8 elems/thread (x fp32 copy no longer needed:
// gemm layer 0 reads node_emb directly as the residual input)
__global__ __launch_bounds__(256) void tobf16_kernel(const float* __restrict__ in,
                                                     __hip_bfloat16* __restrict__ xb) {
  size_t i = (size_t)blockIdx.x * 256 + threadIdx.x;  // 1.6M threads exactly
  const float4* p = (const float4*)in + i * 2;
  float4 a = p[0], b = p[1];
  union { __hip_bfloat16 h[8]; uint4 u; } r;
  r.h[0] = __float2bfloat16(a.x); r.h[1] = __float2bfloat16(a.y);
  r.h[2] = __float2bfloat16(a.z); r.h[3] = __float2bfloat16(a.w);
  r.h[4] = __float2bfloat16(b.x); r.h[5] = __float2bfloat16(b.y);
  r.h[6] = __float2bfloat16(b.z); r.h[7] = __float2bfloat16(b.w);
  ((uint4*)xb)[i] = r.u;
}

// WT[l][col][k] = bf16(W[l][k][col]) — MFMA B-frag wants contiguous k per col
__global__ __launch_bounds__(256) void wt_kernel(const float* __restrict__ W,
                                                 __hip_bfloat16* __restrict__ WT) {
  int l = blockIdx.x;
  const float* Wl = W + (size_t)l * EMB * EMB;
  __hip_bfloat16* WTl = WT + (size_t)l * EMB * EMB;
  for (int i = threadIdx.x; i < EMB * EMB; i += 256) {
    int k = i >> 7, c = i & 127;
    WTl[c * EMB + k] = __float2bfloat16(Wl[i]);
  }
}

// ---------------- per-layer compute ----------------

__device__ __forceinline__ float bf_lo(unsigned int w) { return __uint_as_float(w << 16); }
__device__ __forceinline__ float bf_hi(unsigned int w) { return __uint_as_float(w & 0xFFFF0000u); }

// one wave per node: m[v] = bf16( deg_inv[v] * sum_{u in N(v)} xb[u] )
// 2 rows per vector load (uint2/lane, 32 lanes/row, half-wave per edge);
// 4-pair unroll = 8 edges/iter, 4x 512B loads in flight.
__global__ __launch_bounds__(256) void aggregate_kernel(const __hip_bfloat16* __restrict__ xb,
                                                        const int* __restrict__ row_ptr,
                                                        const int* __restrict__ col,
                                                        const float* __restrict__ deg_inv,
                                                        __hip_bfloat16* __restrict__ mb) {
  int gw = (blockIdx.x * 256 + threadIdx.x) >> 6;
  int lane = threadIdx.x & 63;
  int v = __builtin_amdgcn_readfirstlane(gw);  // wave-uniform node id -> SGPR
  if (v >= N_NODES) return;
  int beg = row_ptr[v];
  int end = row_ptr[v + 1];
  const int half = lane >> 5;   // which edge of a pair this half-wave handles
  const int l31 = lane & 31;
  const char* base = (const char*)xb + l31 * 8;  // 4 bf16 per lane
  float a0 = 0.f, a1 = 0.f, a2 = 0.f, a3 = 0.f;
  int e = beg;
  for (; e + 8 <= end; e += 8) {
    int u0 = col[e + half];
    int u1 = col[e + 2 + half];
    int u2 = col[e + 4 + half];
    int u3 = col[e + 6 + half];
    uint2 w0 = *(const uint2*)(base + (size_t)u0 * (EMB * 2));
    uint2 w1 = *(const uint2*)(base + (size_t)u1 * (EMB * 2));
    uint2 w2 = *(const uint2*)(base + (size_t)u2 * (EMB * 2));
    uint2 w3 = *(const uint2*)(base + (size_t)u3 * (EMB * 2));
    a0 += bf_lo(w0.x) + bf_lo(w1.x) + bf_lo(w2.x) + bf_lo(w3.x);
    a1 += bf_hi(w0.x) + bf_hi(w1.x) + bf_hi(w2.x) + bf_hi(w3.x);
    a2 += bf_lo(w0.y) + bf_lo(w1.y) + bf_lo(w2.y) + bf_lo(w3.y);
    a3 += bf_hi(w0.y) + bf_hi(w1.y) + bf_hi(w2.y) + bf_hi(w3.y);
  }
  for (; e + 2 <= end; e += 2) {
    int u = col[e + half];
    uint2 w = *(const uint2*)(base + (size_t)u * (EMB * 2));
    a0 += bf_lo(w.x); a1 += bf_hi(w.x); a2 += bf_lo(w.y); a3 += bf_hi(w.y);
  }
  if (e < end && half == 0) {  // odd tail: lower half only
    int u = col[e];
    uint2 w = *(const uint2*)(base + (size_t)u * (EMB * 2));
    a0 += bf_lo(w.x); a1 += bf_hi(w.x); a2 += bf_lo(w.y); a3 += bf_hi(w.y);
  }
  a0 += __shfl_xor(a0, 32, 64);
  a1 += __shfl_xor(a1, 32, 64);
  a2 += __shfl_xor(a2, 32, 64);
  a3 += __shfl_xor(a3, 32, 64);
  if (half == 0) {
    float di = deg_inv[v];
    union { __hip_bfloat16 h[4]; uint2 u; } r;
    r.h[0] = __float2bfloat16(a0 * di);
    r.h[1] = __float2bfloat16(a1 * di);
    r.h[2] = __float2bfloat16(a2 * di);
    r.h[3] = __float2bfloat16(a3 * di);
    *(uint2*)((char*)mb + (size_t)v * (EMB * 2) + l31 * 8) = r.u;
  }
}

__device__ __forceinline__ float gelu_exact(float v) {
  return 0.5f * v * (1.f + erff(v * 0.70710678118654752f));
}

// xout[row] = xin[row] + gelu(m[row] @ W + bias)   via bf16 MFMA, fp32 accum.
// 3125 blocks x 32 rows (exact). 4 waves: wave w -> rows (w>>1)*16, cols (w&1)*64.
// B-frags (W^T) in registers. Layer 0 reads node_emb as xin (saves the x copy).
__global__ __launch_bounds__(256) void gemm_kernel(const __hip_bfloat16* __restrict__ mb,
                                                   const __hip_bfloat16* __restrict__ WTl,
                                                   const float* __restrict__ bias,
                                                   const float* xin,
                                                   float* xout,
                                                   __hip_bfloat16* __restrict__ xb,
                                                   int write_xb) {
  const int lane = threadIdx.x & 63;
  const int wave = threadIdx.x >> 6;
  const int rh = wave >> 1;        // row half
  const int ch = wave & 1;         // col half
  const int row0 = blockIdx.x * 32 + rh * 16;
  const int l15 = lane & 15;
  const int lhi = lane >> 4;       // 0..3

  bf16x8 bf[4][4];
#pragma unroll
  for (int ct = 0; ct < 4; ++ct) {
    const __hip_bfloat16* wp = WTl + (size_t)(ch * 64 + ct * 16 + l15) * EMB + lhi * 8;
#pragma unroll
    for (int ks = 0; ks < 4; ++ks)
      bf[ct][ks] = *(const bf16x8*)(wp + ks * 32);
  }

  const bf16x8* ap = (const bf16x8*)(mb + (size_t)(row0 + l15) * EMB + lhi * 8);

  f32x4 acc[4];
#pragma unroll
  for (int ct = 0; ct < 4; ++ct) acc[ct] = (f32x4)(0.f);

#pragma unroll
  for (int ks = 0; ks < 4; ++ks) {
    bf16x8 af = ap[ks * 4];
#pragma unroll
    for (int ct = 0; ct < 4; ++ct)
      acc[ct] = __builtin_amdgcn_mfma_f32_16x16x32_bf16(af, bf[ct][ks], acc[ct], 0, 0, 0);
  }

#pragma unroll
  for (int ct = 0; ct < 4; ++ct) {
    const int colg = ch * 64 + ct * 16 + l15;
    const float bb = bias[colg];
#pragma unroll
    for (int j = 0; j < 4; ++j) {
      const int row = row0 + lhi * 4 + j;
      const size_t off = (size_t)row * EMB + colg;
      float xv = xin[off] + gelu_exact(acc[ct][j] + bb);
      xout[off] = xv;
      if (write_xb) xb[off] = __float2bfloat16(xv);
    }
  }
}

// in-place LayerNorm over feature dim; one wave per row
__global__ __launch_bounds__(256) void ln_kernel(float* __restrict__ x,
                                                 const float* __restrict__ gamma,
                                                 const float* __restrict__ beta) {
  int gw = (blockIdx.x * 256 + threadIdx.x) >> 6;
  int lane = threadIdx.x & 63;
  if (gw >= N_NODES) return;
  float* xp = x + (size_t)gw * EMB + lane * 2;
  float2 v = *(const float2*)xp;
  float s = v.x + v.y;
  float sq = fmaf(v.x, v.x, v.y * v.y);
  for (int off = 1; off < 64; off <<= 1) {
    s += __shfl_xor(s, off, 64);
    sq += __shfl_xor(sq, off, 64);
  }
  float mu = s * (1.f / EMB);
  float var = sq * (1.f / EMB) - mu * mu;
  float rstd = rsqrtf(var + 1e-5f);
  float2 g = *(const float2*)(gamma + lane * 2);
  float2 be = *(const float2*)(beta + lane * 2);
  float2 o;
  o.x = (v.x - mu) * rstd * g.x + be.x;
  o.y = (v.y - mu) * rstd * g.y + be.y;
  *(float2*)xp = o;
}

// ---------------- launch ----------------

extern "C" void kernel_launch(void* const* d_in, const int* in_sizes, int n_in,
                              void* d_out, int out_size, void* d_ws, size_t ws_size,
                              hipStream_t stream) {
  const int* edge_index = (const int*)d_in[0];
  const float* deg_inv = (const float*)d_in[1];
  const float* node_emb = (const float*)d_in[2];
  const float* W = (const float*)d_in[3];
  const float* b = (const float*)d_in[4];
  const float* gamma = (const float*)d_in[5];
  const float* beta = (const float*)d_in[6];
  const int* src = edge_index;
  const int* dst = edge_index + N_EDGES;
  float* x = (float*)d_out;  // fp32 residual stream lives in d_out

  // workspace layout (offsets padded to 256B)
  char* ws = (char*)d_ws;
  auto take = [&](size_t bytes) {
    char* p = ws;
    ws += (bytes + 255) & ~(size_t)255;
    return p;
  };
  __hip_bfloat16* xb = (__hip_bfloat16*)take((size_t)N_NODES * EMB * 2);  // bf16 shadow of x
  __hip_bfloat16* mb = (__hip_bfloat16*)take((size_t)N_NODES * EMB * 2);  // bf16 aggregate
  __hip_bfloat16* WT = (__hip_bfloat16*)take((size_t)N_LAYERS * EMB * EMB * 2);
  int* row_ptr = (int*)take((N_NODES + 1) * sizeof(int));
  int* col = (int*)take(N_EDGES * sizeof(int));
  int* bcur = (int*)take(NB * BSTR * sizeof(int));
  unsigned* pairs = (unsigned*)mb;  // alias: CSR build finishes before layer-0 aggregate
                                    // needs 400*8192*4 = 13.1MB <= 25.6MB ok

  hipMemsetAsync(bcur, 0, NB * BSTR * sizeof(int), stream);

  tobf16_kernel<<<N_NODES * EMB / 8 / 256, 256, 0, stream>>>(node_emb, xb);
  wt_kernel<<<N_LAYERS, 256, 0, stream>>>(W, WT);

  bucket_kernel<<<BUCKET_BLOCKS, BUCKET_THREADS, 0, stream>>>(src, dst, bcur, pairs);
  fillb_kernel<<<NB, 256, 0, stream>>>(pairs, bcur, row_ptr, col);

  for (int l = 0; l < N_LAYERS; ++l) {
    aggregate_kernel<<<(N_NODES + 3) / 4, 256, 0, stream>>>(xb, row_ptr, col, deg_inv, mb);
    gemm_kernel<<<N_NODES / 32, 256, 0, stream>>>(mb, WT + (size_t)l * EMB * EMB,
                                                  b + (size_t)l * EMB,
                                                  l == 0 ? node_emb : x, x, xb,
                                                  l < N_LAYERS - 1 ? 1 : 0);
  }
  ln_kernel<<<(N_NODES + 3) / 4, 256, 0, stream>>>(x, gamma, beta);
}

// Round 8
// 364.322 us; speedup vs baseline: 1.6451x; 1.1163x over previous
//
#include <hip/hip_runtime.h>
#include <hip/hip_bf16.h>
#include <math.h>

#define N_NODES 100000
#define EMB 128
#define N_EDGES 1600000
#define N_LAYERS 3

#define NB 400        // buckets
#define NPB 250       // nodes per bucket
#define CAP 8192      // pairs capacity per bucket (mean 4000, sigma 63)
#define CAPB 6144     // LDS stage capacity (fallback path if exceeded)
#define BSTR 16       // bcur padding stride (64B apart -> parallel L2 atomics)
#define EPT 8
#define BUCKET_THREADS 512
#define BUCKET_BLOCKS ((N_EDGES + BUCKET_THREADS * EPT - 1) / (BUCKET_THREADS * EPT))  // 391

typedef __bf16 bf16x8 __attribute__((ext_vector_type(8)));
typedef float f32x4 __attribute__((ext_vector_type(4)));

// ---------------- CSR build (unchanged from R7: ~25us total) ----------------

__global__ __launch_bounds__(BUCKET_THREADS) void bucket_kernel(
    const int* __restrict__ src, const int* __restrict__ dst,
    int* __restrict__ bcur, unsigned* __restrict__ pairs) {
  __shared__ int scnt[NB];
  __shared__ int sbase[NB];
  const int t = threadIdx.x;
  if (t < NB) scnt[t] = 0;
  __syncthreads();
  unsigned pk[EPT];
  int bk[EPT], lofs[EPT];
  const int base_e = blockIdx.x * BUCKET_THREADS * EPT;
#pragma unroll
  for (int it = 0; it < EPT; ++it) {
    int i = base_e + it * BUCKET_THREADS + t;
    bk[it] = -1;
    if (i < N_EDGES) {
      int d = dst[i];
      int s = src[i];
      int b = d / NPB;
      int vloc = d - b * NPB;
      bk[it] = b;
      pk[it] = ((unsigned)vloc << 17) | (unsigned)s;
      lofs[it] = atomicAdd(&scnt[b], 1);
    }
  }
  __syncthreads();
  if (t < NB) sbase[t] = atomicAdd(&bcur[t * BSTR], scnt[t]);
  __syncthreads();
#pragma unroll
  for (int it = 0; it < EPT; ++it) {
    if (bk[it] >= 0) {
      int idx = sbase[bk[it]] + lofs[it];
      if (idx < CAP) pairs[(size_t)bk[it] * CAP + idx] = pk[it];
    }
  }
}

__device__ __forceinline__ int* scan512(int* pin, int* pout, int t) {
  for (int off = 1; off < 512; off <<= 1) {
    for (int i = t; i < 512; i += 256) {
      int v = pin[i];
      if (i >= off) v += pin[i - off];
      pout[i] = v;
    }
    __syncthreads();
    int* tmp = pin; pin = pout; pout = tmp;
  }
  return pin;
}

__global__ __launch_bounds__(256) void fillb_kernel(const unsigned* __restrict__ pairs,
                                                    const int* __restrict__ bcur,
                                                    int* __restrict__ row_ptr,
                                                    int* __restrict__ col) {
  __shared__ int sA[512], sB[512];
  __shared__ int cnt[NPB], cur[NPB];
  __shared__ unsigned pstage[CAPB];
  __shared__ int colstage[CAPB];
  const int t = threadIdx.x;
  const int b = blockIdx.x;

  for (int i = t; i < 512; i += 256) sA[i] = (i < NB) ? bcur[i * BSTR] : 0;
  __syncthreads();
  int* r = scan512(sA, sB, t);
  int base_b = b ? r[b - 1] : 0;
  int n = r[b] - base_b;
  if (n > CAP) n = CAP;
  const unsigned* pg = pairs + (size_t)b * CAP;
  const bool fits = (n <= CAPB);

  if (fits) for (int i = t; i < n; i += 256) pstage[i] = pg[i];
  if (t < NPB) cnt[t] = 0;
  __syncthreads();
  for (int i = t; i < n; i += 256) atomicAdd(&cnt[(fits ? pstage[i] : pg[i]) >> 17], 1);
  __syncthreads();
  for (int i = t; i < 512; i += 256) sA[i] = (i < NPB) ? cnt[i] : 0;
  __syncthreads();
  r = scan512(sA, sB, t);
  if (t < NPB) {
    int ex = r[t] - cnt[t];
    row_ptr[b * NPB + t] = base_b + ex;
    cur[t] = ex;
  }
  if (b == NB - 1 && t == 0) row_ptr[N_NODES] = N_EDGES;
  __syncthreads();
  for (int i = t; i < n; i += 256) {
    unsigned p = fits ? pstage[i] : pg[i];
    int pos = atomicAdd(&cur[p >> 17], 1);
    int s = (int)(p & 0x1FFFFu);
    if (fits) colstage[pos] = s;
    else col[base_b + pos] = s;
  }
  __syncthreads();
  if (fits) for (int i = t; i < n; i += 256) col[base_b + i] = colstage[i];
}

// ---------------- precompute ----------------

__global__ __launch_bounds__(256) void tobf16_kernel(const float* __restrict__ in,
                                                     __hip_bfloat16* __restrict__ xb) {
  size_t i = (size_t)blockIdx.x * 256 + threadIdx.x;  // 1.6M threads exactly
  const float4* p = (const float4*)in + i * 2;
  float4 a = p[0], b = p[1];
  union { __hip_bfloat16 h[8]; uint4 u; } r;
  r.h[0] = __float2bfloat16(a.x); r.h[1] = __float2bfloat16(a.y);
  r.h[2] = __float2bfloat16(a.z); r.h[3] = __float2bfloat16(a.w);
  r.h[4] = __float2bfloat16(b.x); r.h[5] = __float2bfloat16(b.y);
  r.h[6] = __float2bfloat16(b.z); r.h[7] = __float2bfloat16(b.w);
  ((uint4*)xb)[i] = r.u;
}

__global__ __launch_bounds__(256) void wt_kernel(const float* __restrict__ W,
                                                 __hip_bfloat16* __restrict__ WT) {
  int l = blockIdx.x;
  const float* Wl = W + (size_t)l * EMB * EMB;
  __hip_bfloat16* WTl = WT + (size_t)l * EMB * EMB;
  for (int i = threadIdx.x; i < EMB * EMB; i += 256) {
    int k = i >> 7, c = i & 127;
    WTl[c * EMB + k] = __float2bfloat16(Wl[i]);
  }
}

// ---------------- fused layer: aggregate + GEMM + GELU + residual (+ LN) ----

__device__ __forceinline__ float bf_lo(unsigned int w) { return __uint_as_float(w << 16); }
__device__ __forceinline__ float bf_hi(unsigned int w) { return __uint_as_float(w & 0xFFFF0000u); }

__device__ __forceinline__ float gelu_exact(float v) {
  return 0.5f * v * (1.f + erff(v * 0.70710678118654752f));
}

// Block = 32 rows. Phase 1: 4 waves aggregate 8 nodes each into LDS m-tile
// (quarter-wave uint4 gather: 4 edges/instr, 16-edge unroll = 4x256B in flight).
// Phase 2: MFMA from LDS (pad 136 -> <=2-way bank conflict), B-frags (W^T) in
// registers. Epilogue: residual from bf16 stream; LAST also does LayerNorm
// in-block (rows are LDS-resident) and writes fp32 d_out.
template <int LAST>
__global__ __launch_bounds__(256, 4) void fused_kernel(
    const __hip_bfloat16* __restrict__ xb_in,
    const int* __restrict__ row_ptr,
    const int* __restrict__ col,
    const float* __restrict__ deg_inv,
    const __hip_bfloat16* __restrict__ WTl,
    const float* __restrict__ bias,
    __hip_bfloat16* __restrict__ xb_out,
    float* __restrict__ xf_out,
    const float* __restrict__ gamma,
    const float* __restrict__ beta) {
  __shared__ __hip_bfloat16 sM[32][136];
  __shared__ float sX[32][129];

  const int t = threadIdx.x;
  const int w = t >> 6;         // wave 0..3
  const int lane = t & 63;
  const int q = lane >> 4;      // quarter 0..3 (edge slot / k-group)
  const int l15 = lane & 15;    // col chunk / A-row
  const int row0b = blockIdx.x * 32;

  // ---- phase 1: aggregation (wave w -> m rows w*8 .. w*8+7)
  const char* gbase = (const char*)xb_in + l15 * 16;  // 8 bf16 per lane
  for (int nn = 0; nn < 8; ++nn) {
    const int v = __builtin_amdgcn_readfirstlane(row0b + w * 8 + nn);
    const int beg = row_ptr[v], end = row_ptr[v + 1];
    float a0 = 0.f, a1 = 0.f, a2 = 0.f, a3 = 0.f, a4 = 0.f, a5 = 0.f, a6 = 0.f, a7 = 0.f;
#define ACC8(W) { a0 += bf_lo(W.x); a1 += bf_hi(W.x); a2 += bf_lo(W.y); a3 += bf_hi(W.y); \
                  a4 += bf_lo(W.z); a5 += bf_hi(W.z); a6 += bf_lo(W.w); a7 += bf_hi(W.w); }
    int e = beg;
    for (; e + 16 <= end; e += 16) {
      int u0 = col[e + q];
      int u1 = col[e + 4 + q];
      int u2 = col[e + 8 + q];
      int u3 = col[e + 12 + q];
      uint4 w0 = *(const uint4*)(gbase + (size_t)u0 * 256);
      uint4 w1 = *(const uint4*)(gbase + (size_t)u1 * 256);
      uint4 w2 = *(const uint4*)(gbase + (size_t)u2 * 256);
      uint4 w3 = *(const uint4*)(gbase + (size_t)u3 * 256);
      ACC8(w0) ACC8(w1) ACC8(w2) ACC8(w3)
    }
    for (; e < end; e += 4) {
      int idx = e + q;
      bool valid = idx < end;
      int u = col[valid ? idx : beg];
      uint4 w0 = *(const uint4*)(gbase + (size_t)u * 256);
      if (valid) ACC8(w0)
    }
#undef ACC8
    a0 += __shfl_xor(a0, 16, 64); a0 += __shfl_xor(a0, 32, 64);
    a1 += __shfl_xor(a1, 16, 64); a1 += __shfl_xor(a1, 32, 64);
    a2 += __shfl_xor(a2, 16, 64); a2 += __shfl_xor(a2, 32, 64);
    a3 += __shfl_xor(a3, 16, 64); a3 += __shfl_xor(a3, 32, 64);
    a4 += __shfl_xor(a4, 16, 64); a4 += __shfl_xor(a4, 32, 64);
    a5 += __shfl_xor(a5, 16, 64); a5 += __shfl_xor(a5, 32, 64);
    a6 += __shfl_xor(a6, 16, 64); a6 += __shfl_xor(a6, 32, 64);
    a7 += __shfl_xor(a7, 16, 64); a7 += __shfl_xor(a7, 32, 64);
    if (q == 0) {
      float di = deg_inv[v];
      union { __hip_bfloat16 h[8]; uint4 u4; } r;
      r.h[0] = __float2bfloat16(a0 * di); r.h[1] = __float2bfloat16(a1 * di);
      r.h[2] = __float2bfloat16(a2 * di); r.h[3] = __float2bfloat16(a3 * di);
      r.h[4] = __float2bfloat16(a4 * di); r.h[5] = __float2bfloat16(a5 * di);
      r.h[6] = __float2bfloat16(a6 * di); r.h[7] = __float2bfloat16(a7 * di);
      *(uint4*)(&sM[w * 8 + nn][l15 * 8]) = r.u4;
    }
  }

  // ---- B fragments (issued before barrier; L2-hot, shared by all blocks)
  const int rh = w >> 1, ch = w & 1;
  const int lhi = q;
  bf16x8 bfr[4][4];
#pragma unroll
  for (int ct = 0; ct < 4; ++ct) {
    const __hip_bfloat16* wp = WTl + (size_t)(ch * 64 + ct * 16 + l15) * EMB + lhi * 8;
#pragma unroll
    for (int ks = 0; ks < 4; ++ks)
      bfr[ct][ks] = *(const bf16x8*)(wp + ks * 32);
  }
  __syncthreads();

  // ---- phase 2: MFMA from LDS
  f32x4 acc[4];
#pragma unroll
  for (int ct = 0; ct < 4; ++ct) acc[ct] = (f32x4)(0.f);
#pragma unroll
  for (int ks = 0; ks < 4; ++ks) {
    bf16x8 af = *(const bf16x8*)(&sM[rh * 16 + l15][lhi * 8 + ks * 32]);
#pragma unroll
    for (int ct = 0; ct < 4; ++ct)
      acc[ct] = __builtin_amdgcn_mfma_f32_16x16x32_bf16(af, bfr[ct][ks], acc[ct], 0, 0, 0);
  }

  // ---- epilogue: C[row][col], row = row0b + rh*16 + lhi*4 + j, col = ch*64+ct*16+l15
#pragma unroll
  for (int ct = 0; ct < 4; ++ct) {
    const int colg = ch * 64 + ct * 16 + l15;
    const float bb = bias[colg];
#pragma unroll
    for (int j = 0; j < 4; ++j) {
      const int rloc = rh * 16 + lhi * 4 + j;
      const size_t off = (size_t)(row0b + rloc) * EMB + colg;
      float xv = __bfloat162float(xb_in[off]) + gelu_exact(acc[ct][j] + bb);
      if (!LAST) xb_out[off] = __float2bfloat16(xv);
      else sX[rloc][colg] = xv;
    }
  }

  // ---- fused LayerNorm (last layer): rows are LDS-resident
  if (LAST) {
    __syncthreads();
    float g1 = gamma[lane], g2 = gamma[lane + 64];
    float b1 = beta[lane], b2 = beta[lane + 64];
    for (int rr = 0; rr < 8; ++rr) {
      int r = w * 8 + rr;
      float v1 = sX[r][lane], v2 = sX[r][lane + 64];
      float s = v1 + v2;
      float sq = fmaf(v1, v1, v2 * v2);
      for (int off = 1; off < 64; off <<= 1) {
        s += __shfl_xor(s, off, 64);
        sq += __shfl_xor(sq, off, 64);
      }
      float mu = s * (1.f / EMB);
      float var = sq * (1.f / EMB) - mu * mu;
      float rstd = rsqrtf(var + 1e-5f);
      size_t rowoff = (size_t)(row0b + r) * EMB;
      xf_out[rowoff + lane] = (v1 - mu) * rstd * g1 + b1;
      xf_out[rowoff + lane + 64] = (v2 - mu) * rstd * g2 + b2;
    }
  }
}

// ---------------- launch ----------------

extern "C" void kernel_launch(void* const* d_in, const int* in_sizes, int n_in,
                              void* d_out, int out_size, void* d_ws, size_t ws_size,
                              hipStream_t stream) {
  const int* edge_index = (const int*)d_in[0];
  const float* deg_inv = (const float*)d_in[1];
  const float* node_emb = (const float*)d_in[2];
  const float* W = (const float*)d_in[3];
  const float* b = (const float*)d_in[4];
  const float* gamma = (const float*)d_in[5];
  const float* beta = (const float*)d_in[6];
  const int* src = edge_index;
  const int* dst = edge_index + N_EDGES;
  float* x = (float*)d_out;  // fp32 output written once, post-LN

  char* ws = (char*)d_ws;
  auto take = [&](size_t bytes) {
    char* p = ws;
    ws += (bytes + 255) & ~(size_t)255;
    return p;
  };
  __hip_bfloat16* xbA = (__hip_bfloat16*)take((size_t)N_NODES * EMB * 2);  // bf16 stream ping
  __hip_bfloat16* xbB = (__hip_bfloat16*)take((size_t)N_NODES * EMB * 2);  // bf16 stream pong
  __hip_bfloat16* WT = (__hip_bfloat16*)take((size_t)N_LAYERS * EMB * EMB * 2);
  int* row_ptr = (int*)take((N_NODES + 1) * sizeof(int));
  int* col = (int*)take(N_EDGES * sizeof(int));
  int* bcur = (int*)take(NB * BSTR * sizeof(int));
  unsigned* pairs = (unsigned*)xbB;  // alias: consumed by fillb before layer 0 writes xbB

  hipMemsetAsync(bcur, 0, NB * BSTR * sizeof(int), stream);

  tobf16_kernel<<<N_NODES * EMB / 8 / 256, 256, 0, stream>>>(node_emb, xbA);
  wt_kernel<<<N_LAYERS, 256, 0, stream>>>(W, WT);

  bucket_kernel<<<BUCKET_BLOCKS, BUCKET_THREADS, 0, stream>>>(src, dst, bcur, pairs);
  fillb_kernel<<<NB, 256, 0, stream>>>(pairs, bcur, row_ptr, col);

  const int NBLK = N_NODES / 32;  // 3125, exact
  fused_kernel<0><<<NBLK, 256, 0, stream>>>(xbA, row_ptr, col, deg_inv,
                                            WT, b, xbB, nullptr, nullptr, nullptr);
  fused_kernel<0><<<NBLK, 256, 0, stream>>>(xbB, row_ptr, col, deg_inv,
                                            WT + (size_t)EMB * EMB, b + EMB,
                                            xbA, nullptr, nullptr, nullptr);
  fused_kernel<1><<<NBLK, 256, 0, stream>>>(xbA, row_ptr, col, deg_inv,
                                            WT + (size_t)2 * EMB * EMB, b + 2 * EMB,
                                            nullptr, x, gamma, beta);
}

// Round 9
// 353.921 us; speedup vs baseline: 1.6934x; 1.0294x over previous
//
#include <hip/hip_runtime.h>
#include <hip/hip_bf16.h>
#include <math.h>

#define N_NODES 100000
#define EMB 128
#define N_EDGES 1600000
#define N_LAYERS 3

#define NB 400        // buckets
#define NPB 250       // nodes per bucket
#define CAP 8192      // pairs capacity per bucket (mean 4000, sigma 63)
#define CAPB 6144     // LDS stage capacity (fallback path if exceeded)
#define BSTR 16       // bcur padding stride (64B apart -> parallel L2 atomics)
#define EPT 8
#define BUCKET_THREADS 512
#define BUCKET_BLOCKS ((N_EDGES + BUCKET_THREADS * EPT - 1) / (BUCKET_THREADS * EPT))  // 391

typedef __bf16 bf16x8 __attribute__((ext_vector_type(8)));
typedef float f32x4 __attribute__((ext_vector_type(4)));

// ---------------- CSR build (unchanged: ~25us total) ----------------

__global__ __launch_bounds__(BUCKET_THREADS) void bucket_kernel(
    const int* __restrict__ src, const int* __restrict__ dst,
    int* __restrict__ bcur, unsigned* __restrict__ pairs) {
  __shared__ int scnt[NB];
  __shared__ int sbase[NB];
  const int t = threadIdx.x;
  if (t < NB) scnt[t] = 0;
  __syncthreads();
  unsigned pk[EPT];
  int bk[EPT], lofs[EPT];
  const int base_e = blockIdx.x * BUCKET_THREADS * EPT;
#pragma unroll
  for (int it = 0; it < EPT; ++it) {
    int i = base_e + it * BUCKET_THREADS + t;
    bk[it] = -1;
    if (i < N_EDGES) {
      int d = dst[i];
      int s = src[i];
      int b = d / NPB;
      int vloc = d - b * NPB;
      bk[it] = b;
      pk[it] = ((unsigned)vloc << 17) | (unsigned)s;
      lofs[it] = atomicAdd(&scnt[b], 1);
    }
  }
  __syncthreads();
  if (t < NB) sbase[t] = atomicAdd(&bcur[t * BSTR], scnt[t]);
  __syncthreads();
#pragma unroll
  for (int it = 0; it < EPT; ++it) {
    if (bk[it] >= 0) {
      int idx = sbase[bk[it]] + lofs[it];
      if (idx < CAP) pairs[(size_t)bk[it] * CAP + idx] = pk[it];
    }
  }
}

__device__ __forceinline__ int* scan512(int* pin, int* pout, int t) {
  for (int off = 1; off < 512; off <<= 1) {
    for (int i = t; i < 512; i += 256) {
      int v = pin[i];
      if (i >= off) v += pin[i - off];
      pout[i] = v;
    }
    __syncthreads();
    int* tmp = pin; pin = pout; pout = tmp;
  }
  return pin;
}

__global__ __launch_bounds__(256) void fillb_kernel(const unsigned* __restrict__ pairs,
                                                    const int* __restrict__ bcur,
                                                    int* __restrict__ row_ptr,
                                                    int* __restrict__ col) {
  __shared__ int sA[512], sB[512];
  __shared__ int cnt[NPB], cur[NPB];
  __shared__ unsigned pstage[CAPB];
  __shared__ int colstage[CAPB];
  const int t = threadIdx.x;
  const int b = blockIdx.x;

  for (int i = t; i < 512; i += 256) sA[i] = (i < NB) ? bcur[i * BSTR] : 0;
  __syncthreads();
  int* r = scan512(sA, sB, t);
  int base_b = b ? r[b - 1] : 0;
  int n = r[b] - base_b;
  if (n > CAP) n = CAP;
  const unsigned* pg = pairs + (size_t)b * CAP;
  const bool fits = (n <= CAPB);

  if (fits) for (int i = t; i < n; i += 256) pstage[i] = pg[i];
  if (t < NPB) cnt[t] = 0;
  __syncthreads();
  for (int i = t; i < n; i += 256) atomicAdd(&cnt[(fits ? pstage[i] : pg[i]) >> 17], 1);
  __syncthreads();
  for (int i = t; i < 512; i += 256) sA[i] = (i < NPB) ? cnt[i] : 0;
  __syncthreads();
  r = scan512(sA, sB, t);
  if (t < NPB) {
    int ex = r[t] - cnt[t];
    row_ptr[b * NPB + t] = base_b + ex;
    cur[t] = ex;
  }
  if (b == NB - 1 && t == 0) row_ptr[N_NODES] = N_EDGES;
  __syncthreads();
  for (int i = t; i < n; i += 256) {
    unsigned p = fits ? pstage[i] : pg[i];
    int pos = atomicAdd(&cur[p >> 17], 1);
    int s = (int)(p & 0x1FFFFu);
    if (fits) colstage[pos] = s;
    else col[base_b + pos] = s;
  }
  __syncthreads();
  if (fits) for (int i = t; i < n; i += 256) col[base_b + i] = colstage[i];
}

// ---------------- precompute ----------------

__global__ __launch_bounds__(256) void tobf16_kernel(const float* __restrict__ in,
                                                     __hip_bfloat16* __restrict__ xb) {
  size_t i = (size_t)blockIdx.x * 256 + threadIdx.x;  // 1.6M threads exactly
  const float4* p = (const float4*)in + i * 2;
  float4 a = p[0], b = p[1];
  union { __hip_bfloat16 h[8]; uint4 u; } r;
  r.h[0] = __float2bfloat16(a.x); r.h[1] = __float2bfloat16(a.y);
  r.h[2] = __float2bfloat16(a.z); r.h[3] = __float2bfloat16(a.w);
  r.h[4] = __float2bfloat16(b.x); r.h[5] = __float2bfloat16(b.y);
  r.h[6] = __float2bfloat16(b.z); r.h[7] = __float2bfloat16(b.w);
  ((uint4*)xb)[i] = r.u;
}

__global__ __launch_bounds__(256) void wt_kernel(const float* __restrict__ W,
                                                 __hip_bfloat16* __restrict__ WT) {
  int l = blockIdx.x;
  const float* Wl = W + (size_t)l * EMB * EMB;
  __hip_bfloat16* WTl = WT + (size_t)l * EMB * EMB;
  for (int i = threadIdx.x; i < EMB * EMB; i += 256) {
    int k = i >> 7, c = i & 127;
    WTl[c * EMB + k] = __float2bfloat16(Wl[i]);
  }
}

// ---------------- fused layer: aggregate + GEMM + GELU + residual (+ LN) ----

__device__ __forceinline__ float bf_lo(unsigned int w) { return __uint_as_float(w << 16); }
__device__ __forceinline__ float bf_hi(unsigned int w) { return __uint_as_float(w & 0xFFFF0000u); }

__device__ __forceinline__ float gelu_exact(float v) {
  return 0.5f * v * (1.f + erff(v * 0.70710678118654752f));
}

// Block = 32 rows. Phase 1: 4 waves aggregate 8 nodes each into LDS m-tile.
// Phase 2: MFMA from LDS, B-frags (W^T) in registers.
// MID layers (LAST=0): no sX -> LDS 8.7KB, launch_bounds(256,8) = 32 waves/CU
// (the random gather is latency-bound: fetch rate ~ resident waves; R8's 44%
// occupancy was the 107us. VGPR 48 <= 64 cap).
// LAST: sX for in-block LayerNorm, 25.2KB LDS -> (256,5).
template <int LAST>
__global__ __launch_bounds__(256, LAST ? 5 : 8) void fused_kernel(
    const __hip_bfloat16* __restrict__ xb_in,
    const int* __restrict__ row_ptr,
    const int* __restrict__ col,
    const float* __restrict__ deg_inv,
    const __hip_bfloat16* __restrict__ WTl,
    const float* __restrict__ bias,
    __hip_bfloat16* __restrict__ xb_out,
    float* __restrict__ xf_out,
    const float* __restrict__ gamma,
    const float* __restrict__ beta) {
  __shared__ __hip_bfloat16 sM[32][136];
  __shared__ float sX[LAST ? 32 * 129 : 1];

  const int t = threadIdx.x;
  const int w = t >> 6;         // wave 0..3
  const int lane = t & 63;
  const int q = lane >> 4;      // quarter 0..3 (edge slot / k-group)
  const int l15 = lane & 15;    // col chunk / A-row
  const int row0b = blockIdx.x * 32;

  // ---- phase 1: aggregation (wave w -> m rows w*8 .. w*8+7)
  const char* gbase = (const char*)xb_in + l15 * 16;  // 8 bf16 per lane
  for (int nn = 0; nn < 8; ++nn) {
    const int v = __builtin_amdgcn_readfirstlane(row0b + w * 8 + nn);
    const int beg = row_ptr[v], end = row_ptr[v + 1];
    float a0 = 0.f, a1 = 0.f, a2 = 0.f, a3 = 0.f, a4 = 0.f, a5 = 0.f, a6 = 0.f, a7 = 0.f;
#define ACC8(W) { a0 += bf_lo(W.x); a1 += bf_hi(W.x); a2 += bf_lo(W.y); a3 += bf_hi(W.y); \
                  a4 += bf_lo(W.z); a5 += bf_hi(W.z); a6 += bf_lo(W.w); a7 += bf_hi(W.w); }
    int e = beg;
    for (; e + 16 <= end; e += 16) {
      int u0 = col[e + q];
      int u1 = col[e + 4 + q];
      int u2 = col[e + 8 + q];
      int u3 = col[e + 12 + q];
      uint4 w0 = *(const uint4*)(gbase + (size_t)u0 * 256);
      uint4 w1 = *(const uint4*)(gbase + (size_t)u1 * 256);
      uint4 w2 = *(const uint4*)(gbase + (size_t)u2 * 256);
      uint4 w3 = *(const uint4*)(gbase + (size_t)u3 * 256);
      ACC8(w0) ACC8(w1) ACC8(w2) ACC8(w3)
    }
    for (; e < end; e += 4) {
      int idx = e + q;
      bool valid = idx < end;
      int u = col[valid ? idx : beg];
      uint4 w0 = *(const uint4*)(gbase + (size_t)u * 256);
      if (valid) ACC8(w0)
    }
#undef ACC8
    a0 += __shfl_xor(a0, 16, 64); a0 += __shfl_xor(a0, 32, 64);
    a1 += __shfl_xor(a1, 16, 64); a1 += __shfl_xor(a1, 32, 64);
    a2 += __shfl_xor(a2, 16, 64); a2 += __shfl_xor(a2, 32, 64);
    a3 += __shfl_xor(a3, 16, 64); a3 += __shfl_xor(a3, 32, 64);
    a4 += __shfl_xor(a4, 16, 64); a4 += __shfl_xor(a4, 32, 64);
    a5 += __shfl_xor(a5, 16, 64); a5 += __shfl_xor(a5, 32, 64);
    a6 += __shfl_xor(a6, 16, 64); a6 += __shfl_xor(a6, 32, 64);
    a7 += __shfl_xor(a7, 16, 64); a7 += __shfl_xor(a7, 32, 64);
    if (q == 0) {
      float di = deg_inv[v];
      union { __hip_bfloat16 h[8]; uint4 u4; } r;
      r.h[0] = __float2bfloat16(a0 * di); r.h[1] = __float2bfloat16(a1 * di);
      r.h[2] = __float2bfloat16(a2 * di); r.h[3] = __float2bfloat16(a3 * di);
      r.h[4] = __float2bfloat16(a4 * di); r.h[5] = __float2bfloat16(a5 * di);
      r.h[6] = __float2bfloat16(a6 * di); r.h[7] = __float2bfloat16(a7 * di);
      *(uint4*)(&sM[w * 8 + nn][l15 * 8]) = r.u4;
    }
  }

  // ---- B fragments (issued before barrier; L2-hot, shared by all blocks)
  const int rh = w >> 1, ch = w & 1;
  const int lhi = q;
  bf16x8 bfr[4][4];
#pragma unroll
  for (int ct = 0; ct < 4; ++ct) {
    const __hip_bfloat16* wp = WTl + (size_t)(ch * 64 + ct * 16 + l15) * EMB + lhi * 8;
#pragma unroll
    for (int ks = 0; ks < 4; ++ks)
      bfr[ct][ks] = *(const bf16x8*)(wp + ks * 32);
  }
  __syncthreads();

  // ---- phase 2: MFMA from LDS
  f32x4 acc[4];
#pragma unroll
  for (int ct = 0; ct < 4; ++ct) acc[ct] = (f32x4)(0.f);
#pragma unroll
  for (int ks = 0; ks < 4; ++ks) {
    bf16x8 af = *(const bf16x8*)(&sM[rh * 16 + l15][lhi * 8 + ks * 32]);
#pragma unroll
    for (int ct = 0; ct < 4; ++ct)
      acc[ct] = __builtin_amdgcn_mfma_f32_16x16x32_bf16(af, bfr[ct][ks], acc[ct], 0, 0, 0);
  }

  // ---- epilogue: C[row][col], row = row0b + rh*16 + lhi*4 + j, col = ch*64+ct*16+l15
#pragma unroll
  for (int ct = 0; ct < 4; ++ct) {
    const int colg = ch * 64 + ct * 16 + l15;
    const float bb = bias[colg];
#pragma unroll
    for (int j = 0; j < 4; ++j) {
      const int rloc = rh * 16 + lhi * 4 + j;
      const size_t off = (size_t)(row0b + rloc) * EMB + colg;
      float xv = __bfloat162float(xb_in[off]) + gelu_exact(acc[ct][j] + bb);
      if (!LAST) xb_out[off] = __float2bfloat16(xv);
      else sX[rloc * 129 + colg] = xv;
    }
  }

  // ---- fused LayerNorm (last layer): rows are LDS-resident
  if (LAST) {
    __syncthreads();
    float g1 = gamma[lane], g2 = gamma[lane + 64];
    float b1 = beta[lane], b2 = beta[lane + 64];
    for (int rr = 0; rr < 8; ++rr) {
      int r = w * 8 + rr;
      float v1 = sX[r * 129 + lane], v2 = sX[r * 129 + lane + 64];
      float s = v1 + v2;
      float sq = fmaf(v1, v1, v2 * v2);
      for (int off = 1; off < 64; off <<= 1) {
        s += __shfl_xor(s, off, 64);
        sq += __shfl_xor(sq, off, 64);
      }
      float mu = s * (1.f / EMB);
      float var = sq * (1.f / EMB) - mu * mu;
      float rstd = rsqrtf(var + 1e-5f);
      size_t rowoff = (size_t)(row0b + r) * EMB;
      xf_out[rowoff + lane] = (v1 - mu) * rstd * g1 + b1;
      xf_out[rowoff + lane + 64] = (v2 - mu) * rstd * g2 + b2;
    }
  }
}

// ---------------- launch ----------------

extern "C" void kernel_launch(void* const* d_in, const int* in_sizes, int n_in,
                              void* d_out, int out_size, void* d_ws, size_t ws_size,
                              hipStream_t stream) {
  const int* edge_index = (const int*)d_in[0];
  const float* deg_inv = (const float*)d_in[1];
  const float* node_emb = (const float*)d_in[2];
  const float* W = (const float*)d_in[3];
  const float* b = (const float*)d_in[4];
  const float* gamma = (const float*)d_in[5];
  const float* beta = (const float*)d_in[6];
  const int* src = edge_index;
  const int* dst = edge_index + N_EDGES;
  float* x = (float*)d_out;  // fp32 output written once, post-LN

  char* ws = (char*)d_ws;
  auto take = [&](size_t bytes) {
    char* p = ws;
    ws += (bytes + 255) & ~(size_t)255;
    return p;
  };
  __hip_bfloat16* xbA = (__hip_bfloat16*)take((size_t)N_NODES * EMB * 2);  // bf16 stream ping
  __hip_bfloat16* xbB = (__hip_bfloat16*)take((size_t)N_NODES * EMB * 2);  // bf16 stream pong
  __hip_bfloat16* WT = (__hip_bfloat16*)take((size_t)N_LAYERS * EMB * EMB * 2);
  int* row_ptr = (int*)take((N_NODES + 1) * sizeof(int));
  int* col = (int*)take(N_EDGES * sizeof(int));
  int* bcur = (int*)take(NB * BSTR * sizeof(int));
  unsigned* pairs = (unsigned*)xbB;  // alias: consumed by fillb before layer 0 writes xbB

  hipMemsetAsync(bcur, 0, NB * BSTR * sizeof(int), stream);

  tobf16_kernel<<<N_NODES * EMB / 8 / 256, 256, 0, stream>>>(node_emb, xbA);
  wt_kernel<<<N_LAYERS, 256, 0, stream>>>(W, WT);

  bucket_kernel<<<BUCKET_BLOCKS, BUCKET_THREADS, 0, stream>>>(src, dst, bcur, pairs);
  fillb_kernel<<<NB, 256, 0, stream>>>(pairs, bcur, row_ptr, col);

  const int NBLK = N_NODES / 32;  // 3125, exact
  fused_kernel<0><<<NBLK, 256, 0, stream>>>(xbA, row_ptr, col, deg_inv,
                                            WT, b, xbB, nullptr, nullptr, nullptr);
  fused_kernel<0><<<NBLK, 256, 0, stream>>>(xbB, row_ptr, col, deg_inv,
                                            WT + (size_t)EMB * EMB, b + EMB,
                                            xbA, nullptr, nullptr, nullptr);
  fused_kernel<1><<<NBLK, 256, 0, stream>>>(xbA, row_ptr, col, deg_inv,
                                            WT + (size_t)2 * EMB * EMB, b + 2 * EMB,
                                            nullptr, x, gamma, beta);
}

// Round 10
// 315.701 us; speedup vs baseline: 1.8984x; 1.1211x over previous
//
#include <hip/hip_runtime.h>
#include <hip/hip_bf16.h>
#include <math.h>

#define N_NODES 100000
#define EMB 128
#define N_EDGES 1600000
#define N_LAYERS 3

#define NB 400        // buckets
#define NPB 250       // nodes per bucket
#define CAP 8192      // pairs capacity per bucket (mean 4000, sigma 63)
#define CAPB 6144     // LDS stage capacity (fallback path if exceeded)
#define BSTR 16       // bcur padding stride (64B apart -> parallel L2 atomics)
#define EPT 8
#define BUCKET_THREADS 512
#define BUCKET_BLOCKS ((N_EDGES + BUCKET_THREADS * EPT - 1) / (BUCKET_THREADS * EPT))  // 391

typedef __bf16 bf16x8 __attribute__((ext_vector_type(8)));
typedef float f32x4 __attribute__((ext_vector_type(4)));

// ---------------- CSR build (unchanged: ~25us total) ----------------

__global__ __launch_bounds__(BUCKET_THREADS) void bucket_kernel(
    const int* __restrict__ src, const int* __restrict__ dst,
    int* __restrict__ bcur, unsigned* __restrict__ pairs) {
  __shared__ int scnt[NB];
  __shared__ int sbase[NB];
  const int t = threadIdx.x;
  if (t < NB) scnt[t] = 0;
  __syncthreads();
  unsigned pk[EPT];
  int bk[EPT], lofs[EPT];
  const int base_e = blockIdx.x * BUCKET_THREADS * EPT;
#pragma unroll
  for (int it = 0; it < EPT; ++it) {
    int i = base_e + it * BUCKET_THREADS + t;
    bk[it] = -1;
    if (i < N_EDGES) {
      int d = dst[i];
      int s = src[i];
      int b = d / NPB;
      int vloc = d - b * NPB;
      bk[it] = b;
      pk[it] = ((unsigned)vloc << 17) | (unsigned)s;
      lofs[it] = atomicAdd(&scnt[b], 1);
    }
  }
  __syncthreads();
  if (t < NB) sbase[t] = atomicAdd(&bcur[t * BSTR], scnt[t]);
  __syncthreads();
#pragma unroll
  for (int it = 0; it < EPT; ++it) {
    if (bk[it] >= 0) {
      int idx = sbase[bk[it]] + lofs[it];
      if (idx < CAP) pairs[(size_t)bk[it] * CAP + idx] = pk[it];
    }
  }
}

__device__ __forceinline__ int* scan512(int* pin, int* pout, int t) {
  for (int off = 1; off < 512; off <<= 1) {
    for (int i = t; i < 512; i += 256) {
      int v = pin[i];
      if (i >= off) v += pin[i - off];
      pout[i] = v;
    }
    __syncthreads();
    int* tmp = pin; pin = pout; pout = tmp;
  }
  return pin;
}

__global__ __launch_bounds__(256) void fillb_kernel(const unsigned* __restrict__ pairs,
                                                    const int* __restrict__ bcur,
                                                    int* __restrict__ row_ptr,
                                                    int* __restrict__ col) {
  __shared__ int sA[512], sB[512];
  __shared__ int cnt[NPB], cur[NPB];
  __shared__ unsigned pstage[CAPB];
  __shared__ int colstage[CAPB];
  const int t = threadIdx.x;
  const int b = blockIdx.x;

  for (int i = t; i < 512; i += 256) sA[i] = (i < NB) ? bcur[i * BSTR] : 0;
  __syncthreads();
  int* r = scan512(sA, sB, t);
  int base_b = b ? r[b - 1] : 0;
  int n = r[b] - base_b;
  if (n > CAP) n = CAP;
  const unsigned* pg = pairs + (size_t)b * CAP;
  const bool fits = (n <= CAPB);

  if (fits) for (int i = t; i < n; i += 256) pstage[i] = pg[i];
  if (t < NPB) cnt[t] = 0;
  __syncthreads();
  for (int i = t; i < n; i += 256) atomicAdd(&cnt[(fits ? pstage[i] : pg[i]) >> 17], 1);
  __syncthreads();
  for (int i = t; i < 512; i += 256) sA[i] = (i < NPB) ? cnt[i] : 0;
  __syncthreads();
  r = scan512(sA, sB, t);
  if (t < NPB) {
    int ex = r[t] - cnt[t];
    row_ptr[b * NPB + t] = base_b + ex;
    cur[t] = ex;
  }
  if (b == NB - 1 && t == 0) row_ptr[N_NODES] = N_EDGES;
  __syncthreads();
  for (int i = t; i < n; i += 256) {
    unsigned p = fits ? pstage[i] : pg[i];
    int pos = atomicAdd(&cur[p >> 17], 1);
    int s = (int)(p & 0x1FFFFu);
    if (fits) colstage[pos] = s;
    else col[base_b + pos] = s;
  }
  __syncthreads();
  if (fits) for (int i = t; i < n; i += 256) col[base_b + i] = colstage[i];
}

// ---------------- precompute ----------------

__global__ __launch_bounds__(256) void tobf16_kernel(const float* __restrict__ in,
                                                     __hip_bfloat16* __restrict__ xb) {
  size_t i = (size_t)blockIdx.x * 256 + threadIdx.x;  // 1.6M threads exactly
  const float4* p = (const float4*)in + i * 2;
  float4 a = p[0], b = p[1];
  union { __hip_bfloat16 h[8]; uint4 u; } r;
  r.h[0] = __float2bfloat16(a.x); r.h[1] = __float2bfloat16(a.y);
  r.h[2] = __float2bfloat16(a.z); r.h[3] = __float2bfloat16(a.w);
  r.h[4] = __float2bfloat16(b.x); r.h[5] = __float2bfloat16(b.y);
  r.h[6] = __float2bfloat16(b.z); r.h[7] = __float2bfloat16(b.w);
  ((uint4*)xb)[i] = r.u;
}

__global__ __launch_bounds__(256) void wt_kernel(const float* __restrict__ W,
                                                 __hip_bfloat16* __restrict__ WT) {
  int l = blockIdx.x;
  const float* Wl = W + (size_t)l * EMB * EMB;
  __hip_bfloat16* WTl = WT + (size_t)l * EMB * EMB;
  for (int i = threadIdx.x; i < EMB * EMB; i += 256) {
    int k = i >> 7, c = i & 127;
    WTl[c * EMB + k] = __float2bfloat16(Wl[i]);
  }
}

// ---------------- fused layer: aggregate + GEMM + GELU + residual (+ LN) ----

__device__ __forceinline__ float bf_lo(unsigned int w) { return __uint_as_float(w << 16); }
__device__ __forceinline__ float bf_hi(unsigned int w) { return __uint_as_float(w & 0xFFFF0000u); }

__device__ __forceinline__ float gelu_exact(float v) {
  return 0.5f * v * (1.f + erff(v * 0.70710678118654752f));
}

// Block = 1024 threads (16 waves) owning 32 rows.
// Gather phase: 2 nodes per wave (R9's 8-nodes/wave serialized the memory
// pipe on the per-node shuffle-reduce; standalone 1-node/wave hit 3.0 TB/s).
// MFMA phase: one 16x16 tile per wave (rh = w>>3, ct8 = w&7), B-frags 4x bf16x8.
// launch_bounds(1024, 8 waves/EU) -> 2 blocks/CU = 32 waves/CU, VGPR cap 64.
template <int LAST>
__global__ __launch_bounds__(1024, 8) void fused_kernel(
    const __hip_bfloat16* __restrict__ xb_in,
    const int* __restrict__ row_ptr,
    const int* __restrict__ col,
    const float* __restrict__ deg_inv,
    const __hip_bfloat16* __restrict__ WTl,
    const float* __restrict__ bias,
    __hip_bfloat16* __restrict__ xb_out,
    float* __restrict__ xf_out,
    const float* __restrict__ gamma,
    const float* __restrict__ beta) {
  __shared__ __hip_bfloat16 sM[32][136];
  __shared__ float sX[LAST ? 32 * 129 : 1];

  const int t = threadIdx.x;
  const int w = t >> 6;         // wave 0..15
  const int lane = t & 63;
  const int q = lane >> 4;      // quarter 0..3 (edge slot / k-group)
  const int l15 = lane & 15;    // col chunk / A-row
  const int row0b = blockIdx.x * 32;

  // ---- phase 1: aggregation (wave w -> m rows w*2, w*2+1)
  const char* gbase = (const char*)xb_in + l15 * 16;  // 8 bf16 per lane
  for (int nn = 0; nn < 2; ++nn) {
    const int v = __builtin_amdgcn_readfirstlane(row0b + w * 2 + nn);
    const int beg = row_ptr[v], end = row_ptr[v + 1];
    float a0 = 0.f, a1 = 0.f, a2 = 0.f, a3 = 0.f, a4 = 0.f, a5 = 0.f, a6 = 0.f, a7 = 0.f;
#define ACC8(W) { a0 += bf_lo(W.x); a1 += bf_hi(W.x); a2 += bf_lo(W.y); a3 += bf_hi(W.y); \
                  a4 += bf_lo(W.z); a5 += bf_hi(W.z); a6 += bf_lo(W.w); a7 += bf_hi(W.w); }
    int e = beg;
    for (; e + 16 <= end; e += 16) {
      int u0 = col[e + q];
      int u1 = col[e + 4 + q];
      int u2 = col[e + 8 + q];
      int u3 = col[e + 12 + q];
      uint4 w0 = *(const uint4*)(gbase + (size_t)u0 * 256);
      uint4 w1 = *(const uint4*)(gbase + (size_t)u1 * 256);
      uint4 w2 = *(const uint4*)(gbase + (size_t)u2 * 256);
      uint4 w3 = *(const uint4*)(gbase + (size_t)u3 * 256);
      ACC8(w0) ACC8(w1) ACC8(w2) ACC8(w3)
    }
    for (; e < end; e += 4) {
      int idx = e + q;
      bool valid = idx < end;
      int u = col[valid ? idx : beg];
      uint4 w0 = *(const uint4*)(gbase + (size_t)u * 256);
      if (valid) ACC8(w0)
    }
#undef ACC8
    a0 += __shfl_xor(a0, 16, 64); a0 += __shfl_xor(a0, 32, 64);
    a1 += __shfl_xor(a1, 16, 64); a1 += __shfl_xor(a1, 32, 64);
    a2 += __shfl_xor(a2, 16, 64); a2 += __shfl_xor(a2, 32, 64);
    a3 += __shfl_xor(a3, 16, 64); a3 += __shfl_xor(a3, 32, 64);
    a4 += __shfl_xor(a4, 16, 64); a4 += __shfl_xor(a4, 32, 64);
    a5 += __shfl_xor(a5, 16, 64); a5 += __shfl_xor(a5, 32, 64);
    a6 += __shfl_xor(a6, 16, 64); a6 += __shfl_xor(a6, 32, 64);
    a7 += __shfl_xor(a7, 16, 64); a7 += __shfl_xor(a7, 32, 64);
    if (q == 0) {
      float di = deg_inv[v];
      union { __hip_bfloat16 h[8]; uint4 u4; } r;
      r.h[0] = __float2bfloat16(a0 * di); r.h[1] = __float2bfloat16(a1 * di);
      r.h[2] = __float2bfloat16(a2 * di); r.h[3] = __float2bfloat16(a3 * di);
      r.h[4] = __float2bfloat16(a4 * di); r.h[5] = __float2bfloat16(a5 * di);
      r.h[6] = __float2bfloat16(a6 * di); r.h[7] = __float2bfloat16(a7 * di);
      *(uint4*)(&sM[w * 2 + nn][l15 * 8]) = r.u4;
    }
  }

  // ---- B fragments: wave w -> row-tile rh, col-tile ct8
  const int rh = w >> 3;        // 0..1
  const int ct8 = w & 7;        // 0..7
  bf16x8 bfr[4];
  {
    const __hip_bfloat16* wp = WTl + (size_t)(ct8 * 16 + l15) * EMB + q * 8;
#pragma unroll
    for (int ks = 0; ks < 4; ++ks)
      bfr[ks] = *(const bf16x8*)(wp + ks * 32);
  }
  __syncthreads();

  // ---- phase 2: MFMA from LDS (one 16x16 tile per wave)
  f32x4 acc = (f32x4)(0.f);
#pragma unroll
  for (int ks = 0; ks < 4; ++ks) {
    bf16x8 af = *(const bf16x8*)(&sM[rh * 16 + l15][q * 8 + ks * 32]);
    acc = __builtin_amdgcn_mfma_f32_16x16x32_bf16(af, bfr[ks], acc, 0, 0, 0);
  }

  // ---- epilogue: C[row][col], row = row0b + rh*16 + q*4 + j, col = ct8*16 + l15
  {
    const int colg = ct8 * 16 + l15;
    const float bb = bias[colg];
#pragma unroll
    for (int j = 0; j < 4; ++j) {
      const int rloc = rh * 16 + q * 4 + j;
      const size_t off = (size_t)(row0b + rloc) * EMB + colg;
      float xv = __bfloat162float(xb_in[off]) + gelu_exact(acc[j] + bb);
      if (!LAST) xb_out[off] = __float2bfloat16(xv);
      else sX[rloc * 129 + colg] = xv;
    }
  }

  // ---- fused LayerNorm (last layer): rows are LDS-resident; 2 rows/wave
  if (LAST) {
    __syncthreads();
    float g1 = gamma[lane], g2 = gamma[lane + 64];
    float b1 = beta[lane], b2 = beta[lane + 64];
    for (int rr = 0; rr < 2; ++rr) {
      int r = w * 2 + rr;
      float v1 = sX[r * 129 + lane], v2 = sX[r * 129 + lane + 64];
      float s = v1 + v2;
      float sq = fmaf(v1, v1, v2 * v2);
      for (int off = 1; off < 64; off <<= 1) {
        s += __shfl_xor(s, off, 64);
        sq += __shfl_xor(sq, off, 64);
      }
      float mu = s * (1.f / EMB);
      float var = sq * (1.f / EMB) - mu * mu;
      float rstd = rsqrtf(var + 1e-5f);
      size_t rowoff = (size_t)(row0b + r) * EMB;
      xf_out[rowoff + lane] = (v1 - mu) * rstd * g1 + b1;
      xf_out[rowoff + lane + 64] = (v2 - mu) * rstd * g2 + b2;
    }
  }
}

// ---------------- launch ----------------

extern "C" void kernel_launch(void* const* d_in, const int* in_sizes, int n_in,
                              void* d_out, int out_size, void* d_ws, size_t ws_size,
                              hipStream_t stream) {
  const int* edge_index = (const int*)d_in[0];
  const float* deg_inv = (const float*)d_in[1];
  const float* node_emb = (const float*)d_in[2];
  const float* W = (const float*)d_in[3];
  const float* b = (const float*)d_in[4];
  const float* gamma = (const float*)d_in[5];
  const float* beta = (const float*)d_in[6];
  const int* src = edge_index;
  const int* dst = edge_index + N_EDGES;
  float* x = (float*)d_out;  // fp32 output written once, post-LN

  char* ws = (char*)d_ws;
  auto take = [&](size_t bytes) {
    char* p = ws;
    ws += (bytes + 255) & ~(size_t)255;
    return p;
  };
  __hip_bfloat16* xbA = (__hip_bfloat16*)take((size_t)N_NODES * EMB * 2);  // bf16 stream ping
  __hip_bfloat16* xbB = (__hip_bfloat16*)take((size_t)N_NODES * EMB * 2);  // bf16 stream pong
  __hip_bfloat16* WT = (__hip_bfloat16*)take((size_t)N_LAYERS * EMB * EMB * 2);
  int* row_ptr = (int*)take((N_NODES + 1) * sizeof(int));
  int* col = (int*)take(N_EDGES * sizeof(int));
  int* bcur = (int*)take(NB * BSTR * sizeof(int));
  unsigned* pairs = (unsigned*)xbB;  // alias: consumed by fillb before layer 0 writes xbB

  hipMemsetAsync(bcur, 0, NB * BSTR * sizeof(int), stream);

  tobf16_kernel<<<N_NODES * EMB / 8 / 256, 256, 0, stream>>>(node_emb, xbA);
  wt_kernel<<<N_LAYERS, 256, 0, stream>>>(W, WT);

  bucket_kernel<<<BUCKET_BLOCKS, BUCKET_THREADS, 0, stream>>>(src, dst, bcur, pairs);
  fillb_kernel<<<NB, 256, 0, stream>>>(pairs, bcur, row_ptr, col);

  const int NBLK = N_NODES / 32;  // 3125, exact
  fused_kernel<0><<<NBLK, 1024, 0, stream>>>(xbA, row_ptr, col, deg_inv,
                                             WT, b, xbB, nullptr, nullptr, nullptr);
  fused_kernel<0><<<NBLK, 1024, 0, stream>>>(xbB, row_ptr, col, deg_inv,
                                             WT + (size_t)EMB * EMB, b + EMB,
                                             xbA, nullptr, nullptr, nullptr);
  fused_kernel<1><<<NBLK, 1024, 0, stream>>>(xbA, row_ptr, col, deg_inv,
                                             WT + (size_t)2 * EMB * EMB, b + 2 * EMB,
                                             nullptr, x, gamma, beta);
}